// Round 11
// baseline (125.099 us; speedup 1.0000x reference)
//
#include <hip/hip_runtime.h>
#include <hip/hip_bf16.h>
#include <math.h>

namespace {

constexpr int L   = 200;
constexpr int E   = 64;
constexpr int H1N = 80;
constexpr int H2N = 40;

using short8 = __attribute__((ext_vector_type(8))) short;
using f32x4  = __attribute__((ext_vector_type(4))) float;

__device__ inline unsigned short f2bu(float f) {
    return (unsigned short)__builtin_bit_cast(short, __float2bfloat16(f));   // HW RNE
}

// DPP row_ror add: x += ror_n(x) within each 16-lane row (VALU pipe)
#define ROR_ADD(x, CTRL) do {                                                   \
    int _t = __builtin_amdgcn_update_dpp(0, __builtin_bit_cast(int, (x)),       \
                                         (CTRL), 0xf, 0xf, true);               \
    (x) += __builtin_bit_cast(float, _t); } while (0)

// ---- workspace layout (bytes) ----
constexpr int WS_AF   = 0;        // f32[640*8]  A=(W1_k-W1_d), GEMM1 frag order (K=64)
constexpr int WS_CF   = 20480;    // f32[640*8]  C=W1_p,        GEMM1 frag order
constexpr int WS_W2F  = 40960;    // bf16[576*8] GEMM2 B-frags
constexpr int WS_FLAG = 50176;    // int: 1 if mask is int32, 0 if bytes
constexpr int WS_CQ   = 50432;    // f32 [B][80] cq

// ---- prep: frag packing + cq GEMV + mask-dtype sniff (unchanged from R9) ----
__global__ void k0_prep(const float* __restrict__ W1,
                        const float* __restrict__ W2,
                        const float* __restrict__ q,
                        const float* __restrict__ b1,
                        const void* __restrict__ mask,
                        float* __restrict__ Af,
                        float* __restrict__ Cf,
                        unsigned short* __restrict__ W2f,
                        float* __restrict__ cq_all,
                        int* __restrict__ flagG, int B)
{
    const int id = blockIdx.x * 256 + threadIdx.x;
    if (id < 640) {
        const int u  = id, cc = u >> 6, ln = u & 63;
        const int nt = cc >> 1, ks = cc & 1;
        const int j  = nt * 16 + (ln & 15);
        const int i0 = ks * 32 + (ln >> 4) * 8;
        #pragma unroll
        for (int e = 0; e < 8; ++e) {
            const int i = i0 + e;
            Af[u * 8 + e] = W1[(E + i) * H1N + j] - W1[(2 * E + i) * H1N + j];
            Cf[u * 8 + e] = W1[(3 * E + i) * H1N + j];
        }
    } else if (id < 1216) {
        const int u   = id - 640, cc = u >> 6, ln = u & 63;
        const int nt2 = cc / 3, ks2 = cc % 3;
        const int n   = nt2 * 16 + (ln & 15);
        const int j0  = ks2 * 32 + (ln >> 4) * 8;
        #pragma unroll
        for (int e = 0; e < 8; ++e) {
            const int j = j0 + e;
            W2f[u * 8 + e] = (j < H1N && n < H2N) ? f2bu(W2[j * H2N + n])
                                                  : (unsigned short)0;
        }
    } else {
        const int t = id - 1216;
        if (t > B * 20) return;
        if (t == B * 20) {   // mask dtype sniff, once per launch
            const unsigned char* mb = (const unsigned char*)mask;
            int isI32 = 1;
            for (int i = 0; i < 256; ++i)
                if ((i & 3) && mb[i]) { isI32 = 0; break; }
            flagG[0] = isI32;
            return;
        }
        const int b  = t / 20;
        const int jq = (t - b * 20) * 4;
        const float* qb = q + (size_t)b * E;
        float4 a = *(const float4*)(b1 + jq);
        #pragma unroll 8
        for (int i = 0; i < E; ++i) {
            const float qv = qb[i];
            const float4 wa = *(const float4*)(W1 + i * H1N + jq);
            const float4 wb = *(const float4*)(W1 + (2 * E + i) * H1N + jq);
            a.x += qv * (wa.x + wb.x);
            a.y += qv * (wa.y + wb.y);
            a.z += qv * (wa.z + wb.z);
            a.w += qv * (wa.w + wb.w);
        }
        *(float4*)(cq_all + (size_t)b * H1N + jq) = a;
    }
}

__global__ __launch_bounds__(512, 6)
void attn_main(const float* __restrict__ q,
               const float* __restrict__ kmat,
               const float* __restrict__ vmat,
               const void* __restrict__ mask,
               const float* __restrict__ b2,
               const float* __restrict__ Wf,
               const float* __restrict__ bfp,
               const float* __restrict__ Af,
               const float* __restrict__ Cf,
               const unsigned short* __restrict__ W2fG,
               const float* __restrict__ cq_all,
               const int* __restrict__ flagG,
               float* __restrict__ out)
{
    const int tid  = threadIdx.x;
    const int lane = tid & 63;
    const int wv   = tid >> 6;        // 0..7
    const int g    = lane >> 4;
    const int c    = lane & 15;

    __shared__ short8 Mt[640];                   // 10240 B: folded GEMM1 B-frags (K=64)
    __shared__ unsigned short H1t[8][16][104];   // 26624 B: per-wave H1 tiles
    __shared__ float sc[8][16];                  //   512 B: per-wave per-tile probs
    __shared__ float comb_p[8][64];              //  2048 B
    __shared__ float comb_s[8];

    const int bb = blockIdx.x;                   // one batch per block

    // per-wave H1t K-pad zero (cols 80..95)
    *(unsigned long long*)&H1t[wv][c][80 + g * 4] = 0ULL;

    // ---- fold Mtf = bf16(A + q*C) into LDS (f32 math, frag order; R9 numerics) ----
    const float* qbase = q + (size_t)bb * E;
    for (int u = tid; u < 640; u += 512) {
        const int cc = u >> 6, ln = u & 63;
        const int i0 = (cc & 1) * 32 + (ln >> 4) * 8;
        const float4 a0 = *(const float4*)(Af + u * 8);
        const float4 a1 = *(const float4*)(Af + u * 8 + 4);
        const float4 c0 = *(const float4*)(Cf + u * 8);
        const float4 c1 = *(const float4*)(Cf + u * 8 + 4);
        const float4 q0 = *(const float4*)(qbase + i0);
        const float4 q1 = *(const float4*)(qbase + i0 + 4);
        short8 h;
        h[0] = (short)f2bu(a0.x + q0.x * c0.x);
        h[1] = (short)f2bu(a0.y + q0.y * c0.y);
        h[2] = (short)f2bu(a0.z + q0.z * c0.z);
        h[3] = (short)f2bu(a0.w + q0.w * c0.w);
        h[4] = (short)f2bu(a1.x + q1.x * c1.x);
        h[5] = (short)f2bu(a1.y + q1.y * c1.y);
        h[6] = (short)f2bu(a1.z + q1.z * c1.z);
        h[7] = (short)f2bu(a1.w + q1.w * c1.w);
        Mt[u] = h;
    }

    // ---- per-batch setup (overlaps fold) ----
    const int flagv = flagG[0];
    float cqr[5];
    #pragma unroll
    for (int nt = 0; nt < 5; ++nt)
        cqr[nt] = cq_all[(size_t)bb * H1N + nt * 16 + c];
    float b2r[3], wfr[3];
    #pragma unroll
    for (int nt2 = 0; nt2 < 3; ++nt2) {
        const int nc = nt2 * 16 + c;
        b2r[nt2] = (nc < H2N) ? b2[nc] : 0.f;
        wfr[nt2] = (nc < H2N) ? Wf[nc] : 0.f;
    }
    const float bf0 = bfp[0];
    const short8* W2v = (const short8*)W2fG;     // 9.2 KB, L1-resident
    const float*  kbase = kmat + (size_t)bb * (L * E);
    const float*  vb    = vmat + (size_t)bb * (L * E);
    __syncthreads();

    // ---- fused MLP + unnormalized softmax + PV, per wave (no barriers) ----
    float s_w = 0.f;
    f32x4 oa = f32x4{0.f, 0.f, 0.f, 0.f};

    #pragma unroll
    for (int rt = 0; rt < 2; ++rt) {
        const int t = wv + 8 * rt;                // waves 0..4: 2 tiles; 5..7: 1 tile
        if (t < 13) {
            const int row0 = 16 * t;
            const float4* kp = (const float4*)(kbase + (size_t)min(row0 + c, L - 1) * E);
            const float4 kb0 = kp[2 * g];
            const float4 kb1 = kp[2 * g + 1];
            const float4 kb2 = kp[8 + 2 * g];
            const float4 kb3 = kp[8 + 2 * g + 1];

            short8 ak0, ak1;
            ak0[0] = (short)f2bu(kb0.x); ak0[1] = (short)f2bu(kb0.y);
            ak0[2] = (short)f2bu(kb0.z); ak0[3] = (short)f2bu(kb0.w);
            ak0[4] = (short)f2bu(kb1.x); ak0[5] = (short)f2bu(kb1.y);
            ak0[6] = (short)f2bu(kb1.z); ak0[7] = (short)f2bu(kb1.w);
            ak1[0] = (short)f2bu(kb2.x); ak1[1] = (short)f2bu(kb2.y);
            ak1[2] = (short)f2bu(kb2.z); ak1[3] = (short)f2bu(kb2.w);
            ak1[4] = (short)f2bu(kb3.x); ak1[5] = (short)f2bu(kb3.y);
            ak1[6] = (short)f2bu(kb3.z); ak1[7] = (short)f2bu(kb3.w);

            f32x4 acc1[5];
            #pragma unroll
            for (int nt = 0; nt < 5; ++nt) acc1[nt] = f32x4{0.f, 0.f, 0.f, 0.f};
            #pragma unroll
            for (int nt = 0; nt < 5; ++nt) {
                acc1[nt] = __builtin_amdgcn_mfma_f32_16x16x32_bf16(ak0, Mt[(nt * 2 + 0) * 64 + lane], acc1[nt], 0, 0, 0);
                acc1[nt] = __builtin_amdgcn_mfma_f32_16x16x32_bf16(ak1, Mt[(nt * 2 + 1) * 64 + lane], acc1[nt], 0, 0, 0);
            }

            #pragma unroll
            for (int nt = 0; nt < 5; ++nt)
                #pragma unroll
                for (int r = 0; r < 4; ++r)
                    H1t[wv][4 * g + r][nt * 16 + c] = f2bu(acc1[nt][r] + cqr[nt]);

            // issue v loads for this tile NOW (independent of p; hides under GEMM2+sigmoid)
            const float4 v0 = *(const float4*)(vb + (size_t)min(row0 + 0 + g, L - 1) * E + c * 4);
            const float4 v1 = *(const float4*)(vb + (size_t)min(row0 + 4 + g, L - 1) * E + c * 4);
            const float4 v2 = *(const float4*)(vb + (size_t)min(row0 + 8 + g, L - 1) * E + c * 4);
            const float4 v3 = *(const float4*)(vb + (size_t)min(row0 + 12 + g, L - 1) * E + c * 4);

            f32x4 acc2[3];
            #pragma unroll
            for (int nt2 = 0; nt2 < 3; ++nt2) acc2[nt2] = f32x4{0.f, 0.f, 0.f, 0.f};
            #pragma unroll
            for (int ks2 = 0; ks2 < 3; ++ks2) {
                const short8 a2 = *(const short8*)&H1t[wv][c][ks2 * 32 + g * 8];
                #pragma unroll
                for (int nt2 = 0; nt2 < 3; ++nt2)
                    acc2[nt2] = __builtin_amdgcn_mfma_f32_16x16x32_bf16(a2, W2v[(nt2 * 3 + ks2) * 64 + lane], acc2[nt2], 0, 0, 0);
            }

            float pl0 = 0.f, pl1 = 0.f, pl2 = 0.f, pl3 = 0.f;
            #pragma unroll
            for (int nt2 = 0; nt2 < 3; ++nt2) {
                const float wfv = wfr[nt2], b2v = b2r[nt2];
                pl0 += wfv * __builtin_amdgcn_rcpf(1.f + __expf(-(acc2[nt2][0] + b2v)));
                pl1 += wfv * __builtin_amdgcn_rcpf(1.f + __expf(-(acc2[nt2][1] + b2v)));
                pl2 += wfv * __builtin_amdgcn_rcpf(1.f + __expf(-(acc2[nt2][2] + b2v)));
                pl3 += wfv * __builtin_amdgcn_rcpf(1.f + __expf(-(acc2[nt2][3] + b2v)));
            }
            ROR_ADD(pl0, 0x128); ROR_ADD(pl0, 0x124); ROR_ADD(pl0, 0x122); ROR_ADD(pl0, 0x121);
            ROR_ADD(pl1, 0x128); ROR_ADD(pl1, 0x124); ROR_ADD(pl1, 0x122); ROR_ADD(pl1, 0x121);
            ROR_ADD(pl2, 0x128); ROR_ADD(pl2, 0x124); ROR_ADD(pl2, 0x122); ROR_ADD(pl2, 0x121);
            ROR_ADD(pl3, 0x128); ROR_ADD(pl3, 0x124); ROR_ADD(pl3, 0x122); ROR_ADD(pl3, 0x121);

            // p = (mask || row invalid) ? 0 : exp(logit); logit bounded (|logit|<=|bf|+Sum|Wf|~1.6)
            // FIX vs R10: sc write is UNCONDITIONAL for c<4 — stale-slot bug (tile 12) killed R10.
            float p = 0.f;
            const int rowi = row0 + 4 * g + c;
            if (c < 4) {
                if (rowi < L) {
                    const float myv = (c == 0) ? pl0 : (c == 1) ? pl1 : (c == 2) ? pl2 : pl3;
                    const size_t mi = (size_t)bb * L + rowi;
                    const int mv = flagv ? ((const int*)mask)[mi]
                                         : (int)((const unsigned char*)mask)[mi];
                    if (!mv) p = __expf(bf0 + myv);
                }
                sc[wv][4 * g + c] = p;
            }
            // wave sum of this tile's p (p==0 on c>=4 lanes and invalid/masked rows)
            float ps = p;
            #pragma unroll
            for (int off = 1; off < 64; off <<= 1)
                ps += __shfl_xor(ps, off);
            s_w += ps;

            // PV from regs (rows 4*rr+g; sc entries are 0 for masked/invalid rows)
            const float p0 = sc[wv][0 + g];
            const float p1 = sc[wv][4 + g];
            const float p2 = sc[wv][8 + g];
            const float p3 = sc[wv][12 + g];
            oa[0] += p0 * v0.x + p1 * v1.x + p2 * v2.x + p3 * v3.x;
            oa[1] += p0 * v0.y + p1 * v1.y + p2 * v2.y + p3 * v3.y;
            oa[2] += p0 * v0.z + p1 * v1.z + p2 * v2.z + p3 * v3.z;
            oa[3] += p0 * v0.w + p1 * v1.w + p2 * v2.w + p3 * v3.w;
        }
    }

    // ---- publish per-wave (s, oa) and combine once ----
    #pragma unroll
    for (int j = 0; j < 4; ++j) {
        oa[j] += __shfl_xor(oa[j], 16);
        oa[j] += __shfl_xor(oa[j], 32);
    }
    if (lane < 16)
        *(float4*)&comb_p[wv][4 * lane] = make_float4(oa[0], oa[1], oa[2], oa[3]);
    if (lane == 0) comb_s[wv] = s_w;
    __syncthreads();

    if (tid < 64) {
        float den = comb_s[0];
        float num = comb_p[0][tid];
        #pragma unroll
        for (int w = 1; w < 8; ++w) {
            den += comb_s[w];
            num += comb_p[w][tid];
        }
        out[(size_t)bb * E + tid] = num / den;
    }
}

} // namespace

extern "C" void kernel_launch(void* const* d_in, const int* in_sizes, int n_in,
                              void* d_out, int out_size, void* d_ws, size_t ws_size,
                              hipStream_t stream) {
    const float* q  = (const float*)d_in[0];
    const float* k  = (const float*)d_in[1];
    const float* v  = (const float*)d_in[2];
    const void*  mk = d_in[3];
    const float* W1 = (const float*)d_in[4];
    const float* b1 = (const float*)d_in[5];
    const float* W2 = (const float*)d_in[6];
    const float* b2 = (const float*)d_in[7];
    const float* Wf = (const float*)d_in[8];
    const float* bf = (const float*)d_in[9];
    float* out = (float*)d_out;

    const int B = in_sizes[0] / E;   // 4096

    char* ws = (char*)d_ws;
    float*          Af     = (float*)(ws + WS_AF);
    float*          Cf     = (float*)(ws + WS_CF);
    unsigned short* W2f    = (unsigned short*)(ws + WS_W2F);
    int*            flagG  = (int*)(ws + WS_FLAG);
    float*          cq_all = (float*)(ws + WS_CQ);

    const int prep_ids = 1216 + B * 20 + 1;
    k0_prep<<<(prep_ids + 255) / 256, 256, 0, stream>>>(W1, W2, q, b1, mk,
                                                        Af, Cf, W2f, cq_all, flagG, B);
    attn_main<<<B, 512, 0, stream>>>(q, k, v, mk, b2, Wf, bf,
                                     Af, Cf, W2f, cq_all, flagG, out);
}

// Round 13
// 123.522 us; speedup vs baseline: 1.0128x; 1.0128x over previous
//
#include <hip/hip_runtime.h>
#include <hip/hip_bf16.h>
#include <math.h>

namespace {

constexpr int L   = 200;
constexpr int E   = 64;
constexpr int H1N = 80;
constexpr int H2N = 40;

using short8 = __attribute__((ext_vector_type(8))) short;
using f32x4  = __attribute__((ext_vector_type(4))) float;

__device__ inline unsigned short f2bu(float f) {
    return (unsigned short)__builtin_bit_cast(short, __float2bfloat16(f));   // HW RNE
}

// DPP row_ror add: x += ror_n(x) within each 16-lane row (VALU pipe)
#define ROR_ADD(x, CTRL) do {                                                   \
    int _t = __builtin_amdgcn_update_dpp(0, __builtin_bit_cast(int, (x)),       \
                                         (CTRL), 0xf, 0xf, true);               \
    (x) += __builtin_bit_cast(float, _t); } while (0)

// ---- workspace layout (bytes) ----
constexpr int WS_AF   = 0;        // f32[640*8]  A=(W1_k-W1_d), GEMM1 frag order (K=64)
constexpr int WS_CF   = 20480;    // f32[640*8]  C=W1_p,        GEMM1 frag order
constexpr int WS_W2F  = 40960;    // bf16[576*8] GEMM2 B-frags
constexpr int WS_FLAG = 50176;    // int: 1 if mask is int32, 0 if bytes
constexpr int WS_CQ   = 50432;    // f32 [B][80] cq

// ---- prep: frag packing + cq GEMV + mask-dtype sniff (unchanged from R11) ----
__global__ void k0_prep(const float* __restrict__ W1,
                        const float* __restrict__ W2,
                        const float* __restrict__ q,
                        const float* __restrict__ b1,
                        const void* __restrict__ mask,
                        float* __restrict__ Af,
                        float* __restrict__ Cf,
                        unsigned short* __restrict__ W2f,
                        float* __restrict__ cq_all,
                        int* __restrict__ flagG, int B)
{
    const int id = blockIdx.x * 256 + threadIdx.x;
    if (id < 640) {
        const int u  = id, cc = u >> 6, ln = u & 63;
        const int nt = cc >> 1, ks = cc & 1;
        const int j  = nt * 16 + (ln & 15);
        const int i0 = ks * 32 + (ln >> 4) * 8;
        #pragma unroll
        for (int e = 0; e < 8; ++e) {
            const int i = i0 + e;
            Af[u * 8 + e] = W1[(E + i) * H1N + j] - W1[(2 * E + i) * H1N + j];
            Cf[u * 8 + e] = W1[(3 * E + i) * H1N + j];
        }
    } else if (id < 1216) {
        const int u   = id - 640, cc = u >> 6, ln = u & 63;
        const int nt2 = cc / 3, ks2 = cc % 3;
        const int n   = nt2 * 16 + (ln & 15);
        const int j0  = ks2 * 32 + (ln >> 4) * 8;
        #pragma unroll
        for (int e = 0; e < 8; ++e) {
            const int j = j0 + e;
            W2f[u * 8 + e] = (j < H1N && n < H2N) ? f2bu(W2[j * H2N + n])
                                                  : (unsigned short)0;
        }
    } else {
        const int t = id - 1216;
        if (t > B * 20) return;
        if (t == B * 20) {   // mask dtype sniff, once per launch
            const unsigned char* mb = (const unsigned char*)mask;
            int isI32 = 1;
            for (int i = 0; i < 256; ++i)
                if ((i & 3) && mb[i]) { isI32 = 0; break; }
            flagG[0] = isI32;
            return;
        }
        const int b  = t / 20;
        const int jq = (t - b * 20) * 4;
        const float* qb = q + (size_t)b * E;
        float4 a = *(const float4*)(b1 + jq);
        #pragma unroll 8
        for (int i = 0; i < E; ++i) {
            const float qv = qb[i];
            const float4 wa = *(const float4*)(W1 + i * H1N + jq);
            const float4 wb = *(const float4*)(W1 + (2 * E + i) * H1N + jq);
            a.x += qv * (wa.x + wb.x);
            a.y += qv * (wa.y + wb.y);
            a.z += qv * (wa.z + wb.z);
            a.w += qv * (wa.w + wb.w);
        }
        *(float4*)(cq_all + (size_t)b * H1N + jq) = a;
    }
}

// R11 structure (block-per-batch, 8 waves, tiles wv and wv+8), identical math;
// ONLY change: k/v software prefetch (tile A pre-barrier, tile B during tile A).
__global__ __launch_bounds__(512, 4)
void attn_main(const float* __restrict__ q,
               const float* __restrict__ kmat,
               const float* __restrict__ vmat,
               const void* __restrict__ mask,
               const float* __restrict__ b2,
               const float* __restrict__ Wf,
               const float* __restrict__ bfp,
               const float* __restrict__ Af,
               const float* __restrict__ Cf,
               const unsigned short* __restrict__ W2fG,
               const float* __restrict__ cq_all,
               const int* __restrict__ flagG,
               float* __restrict__ out)
{
    const int tid  = threadIdx.x;
    const int lane = tid & 63;
    const int wv   = tid >> 6;        // 0..7
    const int g    = lane >> 4;
    const int c    = lane & 15;

    __shared__ short8 Mt[640];                   // 10240 B: folded GEMM1 B-frags (K=64)
    __shared__ unsigned short H1t[8][16][104];   // 26624 B: per-wave transpose tiles
    __shared__ float sc[8][16];                  //   512 B
    __shared__ float comb_p[8][64];              //  2048 B
    __shared__ float comb_s[8];

    const int bb = blockIdx.x;                   // one batch per block

    // per-wave H1t K-pad zero (cols 80..95)
    *(unsigned long long*)&H1t[wv][c][80 + g * 4] = 0ULL;

    // ---- fold Mtf = bf16(A + q*C) into LDS (f32 math, frag order; R11 numerics) ----
    const float* qbase = q + (size_t)bb * E;
    for (int u = tid; u < 640; u += 512) {
        const int cc = u >> 6, ln = u & 63;
        const int i0 = (cc & 1) * 32 + (ln >> 4) * 8;
        const float4 a0 = *(const float4*)(Af + u * 8);
        const float4 a1 = *(const float4*)(Af + u * 8 + 4);
        const float4 c0 = *(const float4*)(Cf + u * 8);
        const float4 c1 = *(const float4*)(Cf + u * 8 + 4);
        const float4 q0 = *(const float4*)(qbase + i0);
        const float4 q1 = *(const float4*)(qbase + i0 + 4);
        short8 h;
        h[0] = (short)f2bu(a0.x + q0.x * c0.x);
        h[1] = (short)f2bu(a0.y + q0.y * c0.y);
        h[2] = (short)f2bu(a0.z + q0.z * c0.z);
        h[3] = (short)f2bu(a0.w + q0.w * c0.w);
        h[4] = (short)f2bu(a1.x + q1.x * c1.x);
        h[5] = (short)f2bu(a1.y + q1.y * c1.y);
        h[6] = (short)f2bu(a1.z + q1.z * c1.z);
        h[7] = (short)f2bu(a1.w + q1.w * c1.w);
        Mt[u] = h;
    }

    // ---- per-batch setup ----
    const int flagv = flagG[0];
    float cqr[5];
    #pragma unroll
    for (int nt = 0; nt < 5; ++nt)
        cqr[nt] = cq_all[(size_t)bb * H1N + nt * 16 + c];
    float b2r[3], wfr[3];
    #pragma unroll
    for (int nt2 = 0; nt2 < 3; ++nt2) {
        const int nc = nt2 * 16 + c;
        b2r[nt2] = (nc < H2N) ? b2[nc] : 0.f;
        wfr[nt2] = (nc < H2N) ? Wf[nc] : 0.f;
    }
    const float bf0 = bfp[0];
    const short8* W2v = (const short8*)W2fG;     // 9.2 KB, L1-resident
    const float*  kbase = kmat + (size_t)bb * (L * E);
    const float*  vb    = vmat + (size_t)bb * (L * E);

    // ---- PREFETCH tile A (t=wv) k+v BEFORE the barrier: latency hides under fold ----
    const int tA = wv;                 // always < 13
    const int rowA = 16 * tA;
    const float4* kpa = (const float4*)(kbase + (size_t)min(rowA + c, L - 1) * E);
    const float4 ka0 = kpa[2 * g];
    const float4 ka1 = kpa[2 * g + 1];
    const float4 ka2 = kpa[8 + 2 * g];
    const float4 ka3 = kpa[8 + 2 * g + 1];
    const float4 va0 = *(const float4*)(vb + (size_t)min(rowA + 0 + g, L - 1) * E + c * 4);
    const float4 va1 = *(const float4*)(vb + (size_t)min(rowA + 4 + g, L - 1) * E + c * 4);
    const float4 va2 = *(const float4*)(vb + (size_t)min(rowA + 8 + g, L - 1) * E + c * 4);
    const float4 va3 = *(const float4*)(vb + (size_t)min(rowA + 12 + g, L - 1) * E + c * 4);
    __syncthreads();

    float s_w = 0.f;
    f32x4 oa = f32x4{0.f, 0.f, 0.f, 0.f};

    // ================= tile A (t = wv, always valid) =================
    float4 kb0, kb1, kb2, kb3, vb0, vb1, vb2, vb3;   // tile-B prefetch regs
    {
        const int row0 = rowA;
        short8 ak0, ak1;
        ak0[0] = (short)f2bu(ka0.x); ak0[1] = (short)f2bu(ka0.y);
        ak0[2] = (short)f2bu(ka0.z); ak0[3] = (short)f2bu(ka0.w);
        ak0[4] = (short)f2bu(ka1.x); ak0[5] = (short)f2bu(ka1.y);
        ak0[6] = (short)f2bu(ka1.z); ak0[7] = (short)f2bu(ka1.w);
        ak1[0] = (short)f2bu(ka2.x); ak1[1] = (short)f2bu(ka2.y);
        ak1[2] = (short)f2bu(ka2.z); ak1[3] = (short)f2bu(ka2.w);
        ak1[4] = (short)f2bu(ka3.x); ak1[5] = (short)f2bu(ka3.y);
        ak1[6] = (short)f2bu(ka3.z); ak1[7] = (short)f2bu(ka3.w);

        // ---- issue tile-B k+v prefetch NOW (hides under MFMA1..PV of tile A) ----
        {
            const int tB = wv + 8;     // may be >=13; clamped rows keep loads in-bounds
            const int rowB = 16 * tB;
            const float4* kpb = (const float4*)(kbase + (size_t)min(rowB + c, L - 1) * E);
            kb0 = kpb[2 * g];
            kb1 = kpb[2 * g + 1];
            kb2 = kpb[8 + 2 * g];
            kb3 = kpb[8 + 2 * g + 1];
            vb0 = *(const float4*)(vb + (size_t)min(rowB + 0 + g, L - 1) * E + c * 4);
            vb1 = *(const float4*)(vb + (size_t)min(rowB + 4 + g, L - 1) * E + c * 4);
            vb2 = *(const float4*)(vb + (size_t)min(rowB + 8 + g, L - 1) * E + c * 4);
            vb3 = *(const float4*)(vb + (size_t)min(rowB + 12 + g, L - 1) * E + c * 4);
        }

        f32x4 acc1[5];
        #pragma unroll
        for (int nt = 0; nt < 5; ++nt) acc1[nt] = f32x4{0.f, 0.f, 0.f, 0.f};
        #pragma unroll
        for (int nt = 0; nt < 5; ++nt) {
            acc1[nt] = __builtin_amdgcn_mfma_f32_16x16x32_bf16(ak0, Mt[(nt * 2 + 0) * 64 + lane], acc1[nt], 0, 0, 0);
            acc1[nt] = __builtin_amdgcn_mfma_f32_16x16x32_bf16(ak1, Mt[(nt * 2 + 1) * 64 + lane], acc1[nt], 0, 0, 0);
        }

        #pragma unroll
        for (int nt = 0; nt < 5; ++nt)
            #pragma unroll
            for (int r = 0; r < 4; ++r)
                H1t[wv][4 * g + r][nt * 16 + c] = f2bu(acc1[nt][r] + cqr[nt]);

        f32x4 acc2[3];
        #pragma unroll
        for (int nt2 = 0; nt2 < 3; ++nt2) acc2[nt2] = f32x4{0.f, 0.f, 0.f, 0.f};
        #pragma unroll
        for (int ks2 = 0; ks2 < 3; ++ks2) {
            const short8 a2 = *(const short8*)&H1t[wv][c][ks2 * 32 + g * 8];
            #pragma unroll
            for (int nt2 = 0; nt2 < 3; ++nt2)
                acc2[nt2] = __builtin_amdgcn_mfma_f32_16x16x32_bf16(a2, W2v[(nt2 * 3 + ks2) * 64 + lane], acc2[nt2], 0, 0, 0);
        }

        float pl0 = 0.f, pl1 = 0.f, pl2 = 0.f, pl3 = 0.f;
        #pragma unroll
        for (int nt2 = 0; nt2 < 3; ++nt2) {
            const float wfv = wfr[nt2], b2v = b2r[nt2];
            pl0 += wfv * __builtin_amdgcn_rcpf(1.f + __expf(-(acc2[nt2][0] + b2v)));
            pl1 += wfv * __builtin_amdgcn_rcpf(1.f + __expf(-(acc2[nt2][1] + b2v)));
            pl2 += wfv * __builtin_amdgcn_rcpf(1.f + __expf(-(acc2[nt2][2] + b2v)));
            pl3 += wfv * __builtin_amdgcn_rcpf(1.f + __expf(-(acc2[nt2][3] + b2v)));
        }
        ROR_ADD(pl0, 0x128); ROR_ADD(pl0, 0x124); ROR_ADD(pl0, 0x122); ROR_ADD(pl0, 0x121);
        ROR_ADD(pl1, 0x128); ROR_ADD(pl1, 0x124); ROR_ADD(pl1, 0x122); ROR_ADD(pl1, 0x121);
        ROR_ADD(pl2, 0x128); ROR_ADD(pl2, 0x124); ROR_ADD(pl2, 0x122); ROR_ADD(pl2, 0x121);
        ROR_ADD(pl3, 0x128); ROR_ADD(pl3, 0x124); ROR_ADD(pl3, 0x122); ROR_ADD(pl3, 0x121);

        float p = 0.f;
        const int rowi = row0 + 4 * g + c;
        if (c < 4) {
            if (rowi < L) {
                const float myv = (c == 0) ? pl0 : (c == 1) ? pl1 : (c == 2) ? pl2 : pl3;
                const size_t mi = (size_t)bb * L + rowi;
                const int mv = flagv ? ((const int*)mask)[mi]
                                     : (int)((const unsigned char*)mask)[mi];
                if (!mv) p = __expf(bf0 + myv);
            }
            sc[wv][4 * g + c] = p;
        }
        float ps = p;
        #pragma unroll
        for (int off = 1; off < 64; off <<= 1)
            ps += __shfl_xor(ps, off);
        s_w += ps;

        const float p0 = sc[wv][0 + g];
        const float p1 = sc[wv][4 + g];
        const float p2 = sc[wv][8 + g];
        const float p3 = sc[wv][12 + g];
        oa[0] += p0 * va0.x + p1 * va1.x + p2 * va2.x + p3 * va3.x;
        oa[1] += p0 * va0.y + p1 * va1.y + p2 * va2.y + p3 * va3.y;
        oa[2] += p0 * va0.z + p1 * va1.z + p2 * va2.z + p3 * va3.z;
        oa[3] += p0 * va0.w + p1 * va1.w + p2 * va2.w + p3 * va3.w;
    }

    // ================= tile B (t = wv + 8, valid for wv < 5) =================
    if (wv + 8 < 13) {
        const int row0 = 16 * (wv + 8);
        short8 ak0, ak1;
        ak0[0] = (short)f2bu(kb0.x); ak0[1] = (short)f2bu(kb0.y);
        ak0[2] = (short)f2bu(kb0.z); ak0[3] = (short)f2bu(kb0.w);
        ak0[4] = (short)f2bu(kb1.x); ak0[5] = (short)f2bu(kb1.y);
        ak0[6] = (short)f2bu(kb1.z); ak0[7] = (short)f2bu(kb1.w);
        ak1[0] = (short)f2bu(kb2.x); ak1[1] = (short)f2bu(kb2.y);
        ak1[2] = (short)f2bu(kb2.z); ak1[3] = (short)f2bu(kb2.w);
        ak1[4] = (short)f2bu(kb3.x); ak1[5] = (short)f2bu(kb3.y);
        ak1[6] = (short)f2bu(kb3.z); ak1[7] = (short)f2bu(kb3.w);

        f32x4 acc1[5];
        #pragma unroll
        for (int nt = 0; nt < 5; ++nt) acc1[nt] = f32x4{0.f, 0.f, 0.f, 0.f};
        #pragma unroll
        for (int nt = 0; nt < 5; ++nt) {
            acc1[nt] = __builtin_amdgcn_mfma_f32_16x16x32_bf16(ak0, Mt[(nt * 2 + 0) * 64 + lane], acc1[nt], 0, 0, 0);
            acc1[nt] = __builtin_amdgcn_mfma_f32_16x16x32_bf16(ak1, Mt[(nt * 2 + 1) * 64 + lane], acc1[nt], 0, 0, 0);
        }

        #pragma unroll
        for (int nt = 0; nt < 5; ++nt)
            #pragma unroll
            for (int r = 0; r < 4; ++r)
                H1t[wv][4 * g + r][nt * 16 + c] = f2bu(acc1[nt][r] + cqr[nt]);

        f32x4 acc2[3];
        #pragma unroll
        for (int nt2 = 0; nt2 < 3; ++nt2) acc2[nt2] = f32x4{0.f, 0.f, 0.f, 0.f};
        #pragma unroll
        for (int ks2 = 0; ks2 < 3; ++ks2) {
            const short8 a2 = *(const short8*)&H1t[wv][c][ks2 * 32 + g * 8];
            #pragma unroll
            for (int nt2 = 0; nt2 < 3; ++nt2)
                acc2[nt2] = __builtin_amdgcn_mfma_f32_16x16x32_bf16(a2, W2v[(nt2 * 3 + ks2) * 64 + lane], acc2[nt2], 0, 0, 0);
        }

        float pl0 = 0.f, pl1 = 0.f, pl2 = 0.f, pl3 = 0.f;
        #pragma unroll
        for (int nt2 = 0; nt2 < 3; ++nt2) {
            const float wfv = wfr[nt2], b2v = b2r[nt2];
            pl0 += wfv * __builtin_amdgcn_rcpf(1.f + __expf(-(acc2[nt2][0] + b2v)));
            pl1 += wfv * __builtin_amdgcn_rcpf(1.f + __expf(-(acc2[nt2][1] + b2v)));
            pl2 += wfv * __builtin_amdgcn_rcpf(1.f + __expf(-(acc2[nt2][2] + b2v)));
            pl3 += wfv * __builtin_amdgcn_rcpf(1.f + __expf(-(acc2[nt2][3] + b2v)));
        }
        ROR_ADD(pl0, 0x128); ROR_ADD(pl0, 0x124); ROR_ADD(pl0, 0x122); ROR_ADD(pl0, 0x121);
        ROR_ADD(pl1, 0x128); ROR_ADD(pl1, 0x124); ROR_ADD(pl1, 0x122); ROR_ADD(pl1, 0x121);
        ROR_ADD(pl2, 0x128); ROR_ADD(pl2, 0x124); ROR_ADD(pl2, 0x122); ROR_ADD(pl2, 0x121);
        ROR_ADD(pl3, 0x128); ROR_ADD(pl3, 0x124); ROR_ADD(pl3, 0x122); ROR_ADD(pl3, 0x121);

        float p = 0.f;
        const int rowi = row0 + 4 * g + c;
        if (c < 4) {
            if (rowi < L) {
                const float myv = (c == 0) ? pl0 : (c == 1) ? pl1 : (c == 2) ? pl2 : pl3;
                const size_t mi = (size_t)bb * L + rowi;
                const int mv = flagv ? ((const int*)mask)[mi]
                                     : (int)((const unsigned char*)mask)[mi];
                if (!mv) p = __expf(bf0 + myv);
            }
            sc[wv][4 * g + c] = p;
        }
        float ps = p;
        #pragma unroll
        for (int off = 1; off < 64; off <<= 1)
            ps += __shfl_xor(ps, off);
        s_w += ps;

        const float p0 = sc[wv][0 + g];
        const float p1 = sc[wv][4 + g];
        const float p2 = sc[wv][8 + g];
        const float p3 = sc[wv][12 + g];
        oa[0] += p0 * vb0.x + p1 * vb1.x + p2 * vb2.x + p3 * vb3.x;
        oa[1] += p0 * vb0.y + p1 * vb1.y + p2 * vb2.y + p3 * vb3.y;
        oa[2] += p0 * vb0.z + p1 * vb1.z + p2 * vb2.z + p3 * vb3.z;
        oa[3] += p0 * vb0.w + p1 * vb1.w + p2 * vb2.w + p3 * vb3.w;
    }

    // ---- publish per-wave (s, oa) and combine once (R11 epilogue, unchanged) ----
    #pragma unroll
    for (int j = 0; j < 4; ++j) {
        oa[j] += __shfl_xor(oa[j], 16);
        oa[j] += __shfl_xor(oa[j], 32);
    }
    if (lane < 16)
        *(float4*)&comb_p[wv][4 * lane] = make_float4(oa[0], oa[1], oa[2], oa[3]);
    if (lane == 0) comb_s[wv] = s_w;
    __syncthreads();

    if (tid < 64) {
        float den = comb_s[0];
        float num = comb_p[0][tid];
        #pragma unroll
        for (int w = 1; w < 8; ++w) {
            den += comb_s[w];
            num += comb_p[w][tid];
        }
        out[(size_t)bb * E + tid] = num / den;
    }
}

} // namespace

extern "C" void kernel_launch(void* const* d_in, const int* in_sizes, int n_in,
                              void* d_out, int out_size, void* d_ws, size_t ws_size,
                              hipStream_t stream) {
    const float* q  = (const float*)d_in[0];
    const float* k  = (const float*)d_in[1];
    const float* v  = (const float*)d_in[2];
    const void*  mk = d_in[3];
    const float* W1 = (const float*)d_in[4];
    const float* b1 = (const float*)d_in[5];
    const float* W2 = (const float*)d_in[6];
    const float* b2 = (const float*)d_in[7];
    const float* Wf = (const float*)d_in[8];
    const float* bf = (const float*)d_in[9];
    float* out = (float*)d_out;

    const int B = in_sizes[0] / E;   // 4096

    char* ws = (char*)d_ws;
    float*          Af     = (float*)(ws + WS_AF);
    float*          Cf     = (float*)(ws + WS_CF);
    unsigned short* W2f    = (unsigned short*)(ws + WS_W2F);
    int*            flagG  = (int*)(ws + WS_FLAG);
    float*          cq_all = (float*)(ws + WS_CQ);

    const int prep_ids = 1216 + B * 20 + 1;
    k0_prep<<<(prep_ids + 255) / 256, 256, 0, stream>>>(W1, W2, q, b1, mk,
                                                        Af, Cf, W2f, cq_all, flagG, B);
    attn_main<<<B, 512, 0, stream>>>(q, k, v, mk, b2, Wf, bf,
                                     Af, Cf, W2f, cq_all, flagG, out);
}

// Round 14
// 121.849 us; speedup vs baseline: 1.0267x; 1.0137x over previous
//
#include <hip/hip_runtime.h>
#include <hip/hip_bf16.h>
#include <math.h>

namespace {

constexpr int L   = 200;
constexpr int E   = 64;
constexpr int H1N = 80;
constexpr int H2N = 40;

using short8 = __attribute__((ext_vector_type(8))) short;
using f32x4  = __attribute__((ext_vector_type(4))) float;

__device__ inline unsigned short f2bu(float f) {
    return (unsigned short)__builtin_bit_cast(short, __float2bfloat16(f));   // HW RNE
}

// DPP row_ror add: x += ror_n(x) within each 16-lane row (VALU pipe)
#define ROR_ADD(x, CTRL) do {                                                   \
    int _t = __builtin_amdgcn_update_dpp(0, __builtin_bit_cast(int, (x)),       \
                                         (CTRL), 0xf, 0xf, true);               \
    (x) += __builtin_bit_cast(float, _t); } while (0)

// ---- workspace layout (bytes) ----
constexpr int WS_AF   = 0;        // f32[640*8]  A=(W1_k-W1_d), GEMM1 frag order (K=64)
constexpr int WS_CF   = 20480;    // f32[640*8]  C=W1_p,        GEMM1 frag order
constexpr int WS_W2F  = 40960;    // bf16[576*8] GEMM2 B-frags
constexpr int WS_FLAG = 50176;    // int: 1 if mask is int32, 0 if bytes
constexpr int WS_CQ   = 50432;    // f32 [B][80] cq

// ---- prep: frag packing + cq GEMV + mask-dtype sniff (unchanged from R11) ----
__global__ void k0_prep(const float* __restrict__ W1,
                        const float* __restrict__ W2,
                        const float* __restrict__ q,
                        const float* __restrict__ b1,
                        const void* __restrict__ mask,
                        float* __restrict__ Af,
                        float* __restrict__ Cf,
                        unsigned short* __restrict__ W2f,
                        float* __restrict__ cq_all,
                        int* __restrict__ flagG, int B)
{
    const int id = blockIdx.x * 256 + threadIdx.x;
    if (id < 640) {
        const int u  = id, cc = u >> 6, ln = u & 63;
        const int nt = cc >> 1, ks = cc & 1;
        const int j  = nt * 16 + (ln & 15);
        const int i0 = ks * 32 + (ln >> 4) * 8;
        #pragma unroll
        for (int e = 0; e < 8; ++e) {
            const int i = i0 + e;
            Af[u * 8 + e] = W1[(E + i) * H1N + j] - W1[(2 * E + i) * H1N + j];
            Cf[u * 8 + e] = W1[(3 * E + i) * H1N + j];
        }
    } else if (id < 1216) {
        const int u   = id - 640, cc = u >> 6, ln = u & 63;
        const int nt2 = cc / 3, ks2 = cc % 3;
        const int n   = nt2 * 16 + (ln & 15);
        const int j0  = ks2 * 32 + (ln >> 4) * 8;
        #pragma unroll
        for (int e = 0; e < 8; ++e) {
            const int j = j0 + e;
            W2f[u * 8 + e] = (j < H1N && n < H2N) ? f2bu(W2[j * H2N + n])
                                                  : (unsigned short)0;
        }
    } else {
        const int t = id - 1216;
        if (t > B * 20) return;
        if (t == B * 20) {   // mask dtype sniff, once per launch
            const unsigned char* mb = (const unsigned char*)mask;
            int isI32 = 1;
            for (int i = 0; i < 256; ++i)
                if ((i & 3) && mb[i]) { isI32 = 0; break; }
            flagG[0] = isI32;
            return;
        }
        const int b  = t / 20;
        const int jq = (t - b * 20) * 4;
        const float* qb = q + (size_t)b * E;
        float4 a = *(const float4*)(b1 + jq);
        #pragma unroll 8
        for (int i = 0; i < E; ++i) {
            const float qv = qb[i];
            const float4 wa = *(const float4*)(W1 + i * H1N + jq);
            const float4 wb = *(const float4*)(W1 + (2 * E + i) * H1N + jq);
            a.x += qv * (wa.x + wb.x);
            a.y += qv * (wa.y + wb.y);
            a.z += qv * (wa.z + wb.z);
            a.w += qv * (wa.w + wb.w);
        }
        *(float4*)(cq_all + (size_t)b * H1N + jq) = a;
    }
}

// R13 structure; ONLY change: sched_barrier(0) pins after each prefetch group
// so the compiler cannot sink the loads to their uses (R13: VGPR=52 proved sink).
__global__ __launch_bounds__(512, 4)
void attn_main(const float* __restrict__ q,
               const float* __restrict__ kmat,
               const float* __restrict__ vmat,
               const void* __restrict__ mask,
               const float* __restrict__ b2,
               const float* __restrict__ Wf,
               const float* __restrict__ bfp,
               const float* __restrict__ Af,
               const float* __restrict__ Cf,
               const unsigned short* __restrict__ W2fG,
               const float* __restrict__ cq_all,
               const int* __restrict__ flagG,
               float* __restrict__ out)
{
    const int tid  = threadIdx.x;
    const int lane = tid & 63;
    const int wv   = tid >> 6;        // 0..7
    const int g    = lane >> 4;
    const int c    = lane & 15;

    __shared__ short8 Mt[640];                   // 10240 B: folded GEMM1 B-frags (K=64)
    __shared__ unsigned short H1t[8][16][104];   // 26624 B: per-wave transpose tiles
    __shared__ float sc[8][16];                  //   512 B
    __shared__ float comb_p[8][64];              //  2048 B
    __shared__ float comb_s[8];

    const int bb = blockIdx.x;                   // one batch per block

    // per-wave H1t K-pad zero (cols 80..95)
    *(unsigned long long*)&H1t[wv][c][80 + g * 4] = 0ULL;

    // ---- fold Mtf = bf16(A + q*C) into LDS (f32 math, frag order; R11 numerics) ----
    const float* qbase = q + (size_t)bb * E;
    for (int u = tid; u < 640; u += 512) {
        const int cc = u >> 6, ln = u & 63;
        const int i0 = (cc & 1) * 32 + (ln >> 4) * 8;
        const float4 a0 = *(const float4*)(Af + u * 8);
        const float4 a1 = *(const float4*)(Af + u * 8 + 4);
        const float4 c0 = *(const float4*)(Cf + u * 8);
        const float4 c1 = *(const float4*)(Cf + u * 8 + 4);
        const float4 q0 = *(const float4*)(qbase + i0);
        const float4 q1 = *(const float4*)(qbase + i0 + 4);
        short8 h;
        h[0] = (short)f2bu(a0.x + q0.x * c0.x);
        h[1] = (short)f2bu(a0.y + q0.y * c0.y);
        h[2] = (short)f2bu(a0.z + q0.z * c0.z);
        h[3] = (short)f2bu(a0.w + q0.w * c0.w);
        h[4] = (short)f2bu(a1.x + q1.x * c1.x);
        h[5] = (short)f2bu(a1.y + q1.y * c1.y);
        h[6] = (short)f2bu(a1.z + q1.z * c1.z);
        h[7] = (short)f2bu(a1.w + q1.w * c1.w);
        Mt[u] = h;
    }

    // ---- per-batch setup ----
    const int flagv = flagG[0];
    float cqr[5];
    #pragma unroll
    for (int nt = 0; nt < 5; ++nt)
        cqr[nt] = cq_all[(size_t)bb * H1N + nt * 16 + c];
    float b2r[3], wfr[3];
    #pragma unroll
    for (int nt2 = 0; nt2 < 3; ++nt2) {
        const int nc = nt2 * 16 + c;
        b2r[nt2] = (nc < H2N) ? b2[nc] : 0.f;
        wfr[nt2] = (nc < H2N) ? Wf[nc] : 0.f;
    }
    const float bf0 = bfp[0];
    const short8* W2v = (const short8*)W2fG;     // 9.2 KB, L1-resident
    const float*  kbase = kmat + (size_t)bb * (L * E);
    const float*  vb    = vmat + (size_t)bb * (L * E);

    // ---- PREFETCH tile A (t=wv) k+v BEFORE the barrier ----
    const int tA = wv;                 // always < 13
    const int rowA = 16 * tA;
    const float4* kpa = (const float4*)(kbase + (size_t)min(rowA + c, L - 1) * E);
    const float4 ka0 = kpa[2 * g];
    const float4 ka1 = kpa[2 * g + 1];
    const float4 ka2 = kpa[8 + 2 * g];
    const float4 ka3 = kpa[8 + 2 * g + 1];
    const float4 va0 = *(const float4*)(vb + (size_t)min(rowA + 0 + g, L - 1) * E + c * 4);
    const float4 va1 = *(const float4*)(vb + (size_t)min(rowA + 4 + g, L - 1) * E + c * 4);
    const float4 va2 = *(const float4*)(vb + (size_t)min(rowA + 8 + g, L - 1) * E + c * 4);
    const float4 va3 = *(const float4*)(vb + (size_t)min(rowA + 12 + g, L - 1) * E + c * 4);
    __builtin_amdgcn_sched_barrier(0);   // PIN: loads may not sink past this point
    __syncthreads();

    float s_w = 0.f;
    f32x4 oa = f32x4{0.f, 0.f, 0.f, 0.f};

    // ================= tile A (t = wv, always valid) =================
    float4 kb0, kb1, kb2, kb3, vb0, vb1, vb2, vb3;   // tile-B prefetch regs
    {
        const int row0 = rowA;

        // ---- issue tile-B k+v prefetch FIRST, then pin ----
        {
            const int tB = wv + 8;     // may be >=13; clamped rows keep loads in-bounds
            const int rowB = 16 * tB;
            const float4* kpb = (const float4*)(kbase + (size_t)min(rowB + c, L - 1) * E);
            kb0 = kpb[2 * g];
            kb1 = kpb[2 * g + 1];
            kb2 = kpb[8 + 2 * g];
            kb3 = kpb[8 + 2 * g + 1];
            vb0 = *(const float4*)(vb + (size_t)min(rowB + 0 + g, L - 1) * E + c * 4);
            vb1 = *(const float4*)(vb + (size_t)min(rowB + 4 + g, L - 1) * E + c * 4);
            vb2 = *(const float4*)(vb + (size_t)min(rowB + 8 + g, L - 1) * E + c * 4);
            vb3 = *(const float4*)(vb + (size_t)min(rowB + 12 + g, L - 1) * E + c * 4);
        }
        __builtin_amdgcn_sched_barrier(0);   // PIN tile-B loads here (issue-early)

        short8 ak0, ak1;
        ak0[0] = (short)f2bu(ka0.x); ak0[1] = (short)f2bu(ka0.y);
        ak0[2] = (short)f2bu(ka0.z); ak0[3] = (short)f2bu(ka0.w);
        ak0[4] = (short)f2bu(ka1.x); ak0[5] = (short)f2bu(ka1.y);
        ak0[6] = (short)f2bu(ka1.z); ak0[7] = (short)f2bu(ka1.w);
        ak1[0] = (short)f2bu(ka2.x); ak1[1] = (short)f2bu(ka2.y);
        ak1[2] = (short)f2bu(ka2.z); ak1[3] = (short)f2bu(ka2.w);
        ak1[4] = (short)f2bu(ka3.x); ak1[5] = (short)f2bu(ka3.y);
        ak1[6] = (short)f2bu(ka3.z); ak1[7] = (short)f2bu(ka3.w);

        f32x4 acc1[5];
        #pragma unroll
        for (int nt = 0; nt < 5; ++nt) acc1[nt] = f32x4{0.f, 0.f, 0.f, 0.f};
        #pragma unroll
        for (int nt = 0; nt < 5; ++nt) {
            acc1[nt] = __builtin_amdgcn_mfma_f32_16x16x32_bf16(ak0, Mt[(nt * 2 + 0) * 64 + lane], acc1[nt], 0, 0, 0);
            acc1[nt] = __builtin_amdgcn_mfma_f32_16x16x32_bf16(ak1, Mt[(nt * 2 + 1) * 64 + lane], acc1[nt], 0, 0, 0);
        }

        #pragma unroll
        for (int nt = 0; nt < 5; ++nt)
            #pragma unroll
            for (int r = 0; r < 4; ++r)
                H1t[wv][4 * g + r][nt * 16 + c] = f2bu(acc1[nt][r] + cqr[nt]);

        f32x4 acc2[3];
        #pragma unroll
        for (int nt2 = 0; nt2 < 3; ++nt2) acc2[nt2] = f32x4{0.f, 0.f, 0.f, 0.f};
        #pragma unroll
        for (int ks2 = 0; ks2 < 3; ++ks2) {
            const short8 a2 = *(const short8*)&H1t[wv][c][ks2 * 32 + g * 8];
            #pragma unroll
            for (int nt2 = 0; nt2 < 3; ++nt2)
                acc2[nt2] = __builtin_amdgcn_mfma_f32_16x16x32_bf16(a2, W2v[(nt2 * 3 + ks2) * 64 + lane], acc2[nt2], 0, 0, 0);
        }

        float pl0 = 0.f, pl1 = 0.f, pl2 = 0.f, pl3 = 0.f;
        #pragma unroll
        for (int nt2 = 0; nt2 < 3; ++nt2) {
            const float wfv = wfr[nt2], b2v = b2r[nt2];
            pl0 += wfv * __builtin_amdgcn_rcpf(1.f + __expf(-(acc2[nt2][0] + b2v)));
            pl1 += wfv * __builtin_amdgcn_rcpf(1.f + __expf(-(acc2[nt2][1] + b2v)));
            pl2 += wfv * __builtin_amdgcn_rcpf(1.f + __expf(-(acc2[nt2][2] + b2v)));
            pl3 += wfv * __builtin_amdgcn_rcpf(1.f + __expf(-(acc2[nt2][3] + b2v)));
        }
        ROR_ADD(pl0, 0x128); ROR_ADD(pl0, 0x124); ROR_ADD(pl0, 0x122); ROR_ADD(pl0, 0x121);
        ROR_ADD(pl1, 0x128); ROR_ADD(pl1, 0x124); ROR_ADD(pl1, 0x122); ROR_ADD(pl1, 0x121);
        ROR_ADD(pl2, 0x128); ROR_ADD(pl2, 0x124); ROR_ADD(pl2, 0x122); ROR_ADD(pl2, 0x121);
        ROR_ADD(pl3, 0x128); ROR_ADD(pl3, 0x124); ROR_ADD(pl3, 0x122); ROR_ADD(pl3, 0x121);

        float p = 0.f;
        const int rowi = row0 + 4 * g + c;
        if (c < 4) {
            if (rowi < L) {
                const float myv = (c == 0) ? pl0 : (c == 1) ? pl1 : (c == 2) ? pl2 : pl3;
                const size_t mi = (size_t)bb * L + rowi;
                const int mv = flagv ? ((const int*)mask)[mi]
                                     : (int)((const unsigned char*)mask)[mi];
                if (!mv) p = __expf(bf0 + myv);
            }
            sc[wv][4 * g + c] = p;
        }
        float ps = p;
        #pragma unroll
        for (int off = 1; off < 64; off <<= 1)
            ps += __shfl_xor(ps, off);
        s_w += ps;

        const float p0 = sc[wv][0 + g];
        const float p1 = sc[wv][4 + g];
        const float p2 = sc[wv][8 + g];
        const float p3 = sc[wv][12 + g];
        oa[0] += p0 * va0.x + p1 * va1.x + p2 * va2.x + p3 * va3.x;
        oa[1] += p0 * va0.y + p1 * va1.y + p2 * va2.y + p3 * va3.y;
        oa[2] += p0 * va0.z + p1 * va1.z + p2 * va2.z + p3 * va3.z;
        oa[3] += p0 * va0.w + p1 * va1.w + p2 * va2.w + p3 * va3.w;
    }

    // ================= tile B (t = wv + 8, valid for wv < 5) =================
    if (wv + 8 < 13) {
        const int row0 = 16 * (wv + 8);
        short8 ak0, ak1;
        ak0[0] = (short)f2bu(kb0.x); ak0[1] = (short)f2bu(kb0.y);
        ak0[2] = (short)f2bu(kb0.z); ak0[3] = (short)f2bu(kb0.w);
        ak0[4] = (short)f2bu(kb1.x); ak0[5] = (short)f2bu(kb1.y);
        ak0[6] = (short)f2bu(kb1.z); ak0[7] = (short)f2bu(kb1.w);
        ak1[0] = (short)f2bu(kb2.x); ak1[1] = (short)f2bu(kb2.y);
        ak1[2] = (short)f2bu(kb2.z); ak1[3] = (short)f2bu(kb2.w);
        ak1[4] = (short)f2bu(kb3.x); ak1[5] = (short)f2bu(kb3.y);
        ak1[6] = (short)f2bu(kb3.z); ak1[7] = (short)f2bu(kb3.w);

        f32x4 acc1[5];
        #pragma unroll
        for (int nt = 0; nt < 5; ++nt) acc1[nt] = f32x4{0.f, 0.f, 0.f, 0.f};
        #pragma unroll
        for (int nt = 0; nt < 5; ++nt) {
            acc1[nt] = __builtin_amdgcn_mfma_f32_16x16x32_bf16(ak0, Mt[(nt * 2 + 0) * 64 + lane], acc1[nt], 0, 0, 0);
            acc1[nt] = __builtin_amdgcn_mfma_f32_16x16x32_bf16(ak1, Mt[(nt * 2 + 1) * 64 + lane], acc1[nt], 0, 0, 0);
        }

        #pragma unroll
        for (int nt = 0; nt < 5; ++nt)
            #pragma unroll
            for (int r = 0; r < 4; ++r)
                H1t[wv][4 * g + r][nt * 16 + c] = f2bu(acc1[nt][r] + cqr[nt]);

        f32x4 acc2[3];
        #pragma unroll
        for (int nt2 = 0; nt2 < 3; ++nt2) acc2[nt2] = f32x4{0.f, 0.f, 0.f, 0.f};
        #pragma unroll
        for (int ks2 = 0; ks2 < 3; ++ks2) {
            const short8 a2 = *(const short8*)&H1t[wv][c][ks2 * 32 + g * 8];
            #pragma unroll
            for (int nt2 = 0; nt2 < 3; ++nt2)
                acc2[nt2] = __builtin_amdgcn_mfma_f32_16x16x32_bf16(a2, W2v[(nt2 * 3 + ks2) * 64 + lane], acc2[nt2], 0, 0, 0);
        }

        float pl0 = 0.f, pl1 = 0.f, pl2 = 0.f, pl3 = 0.f;
        #pragma unroll
        for (int nt2 = 0; nt2 < 3; ++nt2) {
            const float wfv = wfr[nt2], b2v = b2r[nt2];
            pl0 += wfv * __builtin_amdgcn_rcpf(1.f + __expf(-(acc2[nt2][0] + b2v)));
            pl1 += wfv * __builtin_amdgcn_rcpf(1.f + __expf(-(acc2[nt2][1] + b2v)));
            pl2 += wfv * __builtin_amdgcn_rcpf(1.f + __expf(-(acc2[nt2][2] + b2v)));
            pl3 += wfv * __builtin_amdgcn_rcpf(1.f + __expf(-(acc2[nt2][3] + b2v)));
        }
        ROR_ADD(pl0, 0x128); ROR_ADD(pl0, 0x124); ROR_ADD(pl0, 0x122); ROR_ADD(pl0, 0x121);
        ROR_ADD(pl1, 0x128); ROR_ADD(pl1, 0x124); ROR_ADD(pl1, 0x122); ROR_ADD(pl1, 0x121);
        ROR_ADD(pl2, 0x128); ROR_ADD(pl2, 0x124); ROR_ADD(pl2, 0x122); ROR_ADD(pl2, 0x121);
        ROR_ADD(pl3, 0x128); ROR_ADD(pl3, 0x124); ROR_ADD(pl3, 0x122); ROR_ADD(pl3, 0x121);

        float p = 0.f;
        const int rowi = row0 + 4 * g + c;
        if (c < 4) {
            if (rowi < L) {
                const float myv = (c == 0) ? pl0 : (c == 1) ? pl1 : (c == 2) ? pl2 : pl3;
                const size_t mi = (size_t)bb * L + rowi;
                const int mv = flagv ? ((const int*)mask)[mi]
                                     : (int)((const unsigned char*)mask)[mi];
                if (!mv) p = __expf(bf0 + myv);
            }
            sc[wv][4 * g + c] = p;
        }
        float ps = p;
        #pragma unroll
        for (int off = 1; off < 64; off <<= 1)
            ps += __shfl_xor(ps, off);
        s_w += ps;

        const float p0 = sc[wv][0 + g];
        const float p1 = sc[wv][4 + g];
        const float p2 = sc[wv][8 + g];
        const float p3 = sc[wv][12 + g];
        oa[0] += p0 * vb0.x + p1 * vb1.x + p2 * vb2.x + p3 * vb3.x;
        oa[1] += p0 * vb0.y + p1 * vb1.y + p2 * vb2.y + p3 * vb3.y;
        oa[2] += p0 * vb0.z + p1 * vb1.z + p2 * vb2.z + p3 * vb3.z;
        oa[3] += p0 * vb0.w + p1 * vb1.w + p2 * vb2.w + p3 * vb3.w;
    }

    // ---- publish per-wave (s, oa) and combine once ----
    #pragma unroll
    for (int j = 0; j < 4; ++j) {
        oa[j] += __shfl_xor(oa[j], 16);
        oa[j] += __shfl_xor(oa[j], 32);
    }
    if (lane < 16)
        *(float4*)&comb_p[wv][4 * lane] = make_float4(oa[0], oa[1], oa[2], oa[3]);
    if (lane == 0) comb_s[wv] = s_w;
    __syncthreads();

    if (tid < 64) {
        float den = comb_s[0];
        float num = comb_p[0][tid];
        #pragma unroll
        for (int w = 1; w < 8; ++w) {
            den += comb_s[w];
            num += comb_p[w][tid];
        }
        out[(size_t)bb * E + tid] = num / den;
    }
}

} // namespace

extern "C" void kernel_launch(void* const* d_in, const int* in_sizes, int n_in,
                              void* d_out, int out_size, void* d_ws, size_t ws_size,
                              hipStream_t stream) {
    const float* q  = (const float*)d_in[0];
    const float* k  = (const float*)d_in[1];
    const float* v  = (const float*)d_in[2];
    const void*  mk = d_in[3];
    const float* W1 = (const float*)d_in[4];
    const float* b1 = (const float*)d_in[5];
    const float* W2 = (const float*)d_in[6];
    const float* b2 = (const float*)d_in[7];
    const float* Wf = (const float*)d_in[8];
    const float* bf = (const float*)d_in[9];
    float* out = (float*)d_out;

    const int B = in_sizes[0] / E;   // 4096

    char* ws = (char*)d_ws;
    float*          Af     = (float*)(ws + WS_AF);
    float*          Cf     = (float*)(ws + WS_CF);
    unsigned short* W2f    = (unsigned short*)(ws + WS_W2F);
    int*            flagG  = (int*)(ws + WS_FLAG);
    float*          cq_all = (float*)(ws + WS_CQ);

    const int prep_ids = 1216 + B * 20 + 1;
    k0_prep<<<(prep_ids + 255) / 256, 256, 0, stream>>>(W1, W2, q, b1, mk,
                                                        Af, Cf, W2f, cq_all, flagG, B);
    attn_main<<<B, 512, 0, stream>>>(q, k, v, mk, b2, Wf, bf,
                                     Af, Cf, W2f, cq_all, flagG, out);
}

// Round 16
// 121.378 us; speedup vs baseline: 1.0307x; 1.0039x over previous
//
#include <hip/hip_runtime.h>
#include <hip/hip_bf16.h>
#include <math.h>

namespace {

constexpr int L   = 200;
constexpr int E   = 64;
constexpr int H1N = 80;
constexpr int H2N = 40;

using short8 = __attribute__((ext_vector_type(8))) short;
using f32x4  = __attribute__((ext_vector_type(4))) float;

__device__ inline unsigned short f2bu(float f) {
    return (unsigned short)__builtin_bit_cast(short, __float2bfloat16(f));   // HW RNE
}

// DPP row_ror add: x += ror_n(x) within each 16-lane row (VALU pipe)
#define ROR_ADD(x, CTRL) do {                                                   \
    int _t = __builtin_amdgcn_update_dpp(0, __builtin_bit_cast(int, (x)),       \
                                         (CTRL), 0xf, 0xf, true);               \
    (x) += __builtin_bit_cast(float, _t); } while (0)

// ---- workspace layout (bytes) ----
constexpr int WS_AF   = 0;        // f32[640*8]  A=(W1_k-W1_d), GEMM1 frag order (K=64)
constexpr int WS_CF   = 20480;    // f32[640*8]  C=W1_p,        GEMM1 frag order
constexpr int WS_W2F  = 40960;    // bf16[576*8] GEMM2 B-frags
constexpr int WS_FLAG = 50176;    // int: 1 if mask is int32, 0 if bytes
constexpr int WS_CQ   = 50432;    // f32 [B][80] cq

// ---- prep: frag packing + cq GEMV + mask-dtype sniff (unchanged) ----
__global__ void k0_prep(const float* __restrict__ W1,
                        const float* __restrict__ W2,
                        const float* __restrict__ q,
                        const float* __restrict__ b1,
                        const void* __restrict__ mask,
                        float* __restrict__ Af,
                        float* __restrict__ Cf,
                        unsigned short* __restrict__ W2f,
                        float* __restrict__ cq_all,
                        int* __restrict__ flagG, int B)
{
    const int id = blockIdx.x * 256 + threadIdx.x;
    if (id < 640) {
        const int u  = id, cc = u >> 6, ln = u & 63;
        const int nt = cc >> 1, ks = cc & 1;
        const int j  = nt * 16 + (ln & 15);
        const int i0 = ks * 32 + (ln >> 4) * 8;
        #pragma unroll
        for (int e = 0; e < 8; ++e) {
            const int i = i0 + e;
            Af[u * 8 + e] = W1[(E + i) * H1N + j] - W1[(2 * E + i) * H1N + j];
            Cf[u * 8 + e] = W1[(3 * E + i) * H1N + j];
        }
    } else if (id < 1216) {
        const int u   = id - 640, cc = u >> 6, ln = u & 63;
        const int nt2 = cc / 3, ks2 = cc % 3;
        const int n   = nt2 * 16 + (ln & 15);
        const int j0  = ks2 * 32 + (ln >> 4) * 8;
        #pragma unroll
        for (int e = 0; e < 8; ++e) {
            const int j = j0 + e;
            W2f[u * 8 + e] = (j < H1N && n < H2N) ? f2bu(W2[j * H2N + n])
                                                  : (unsigned short)0;
        }
    } else {
        const int t = id - 1216;
        if (t > B * 20) return;
        if (t == B * 20) {   // mask dtype sniff, once per launch
            const unsigned char* mb = (const unsigned char*)mask;
            int isI32 = 1;
            for (int i = 0; i < 256; ++i)
                if ((i & 3) && mb[i]) { isI32 = 0; break; }
            flagG[0] = isI32;
            return;
        }
        const int b  = t / 20;
        const int jq = (t - b * 20) * 4;
        const float* qb = q + (size_t)b * E;
        float4 a = *(const float4*)(b1 + jq);
        #pragma unroll 8
        for (int i = 0; i < E; ++i) {
            const float qv = qb[i];
            const float4 wa = *(const float4*)(W1 + i * H1N + jq);
            const float4 wb = *(const float4*)(W1 + (2 * E + i) * H1N + jq);
            a.x += qv * (wa.x + wb.x);
            a.y += qv * (wa.y + wb.y);
            a.z += qv * (wa.z + wb.z);
            a.w += qv * (wa.w + wb.w);
        }
        *(float4*)(cq_all + (size_t)b * H1N + jq) = a;
    }
}

// R14 structure (passed, 121.8us). Changes: (1) p broadcast via __shfl instead of
// the sc[] LDS bounce (same values, no LDS WAR pattern); (2) launch_bounds (512,2)
// so the 128-VGPR cap no longer forces the compiler to sink the prefetch loads.
__global__ __launch_bounds__(512, 2)
void attn_main(const float* __restrict__ q,
               const float* __restrict__ kmat,
               const float* __restrict__ vmat,
               const void* __restrict__ mask,
               const float* __restrict__ b2,
               const float* __restrict__ Wf,
               const float* __restrict__ bfp,
               const float* __restrict__ Af,
               const float* __restrict__ Cf,
               const unsigned short* __restrict__ W2fG,
               const float* __restrict__ cq_all,
               const int* __restrict__ flagG,
               float* __restrict__ out)
{
    const int tid  = threadIdx.x;
    const int lane = tid & 63;
    const int wv   = tid >> 6;        // 0..7
    const int g    = lane >> 4;
    const int c    = lane & 15;

    __shared__ short8 Mt[640];                   // 10240 B
    __shared__ unsigned short H1t[8][16][104];   // 26624 B
    __shared__ float comb_p[8][64];              //  2048 B
    __shared__ float comb_s[8];

    const int bb = blockIdx.x;                   // one batch per block

    *(unsigned long long*)&H1t[wv][c][80 + g * 4] = 0ULL;   // K-pad cols 80..95

    // ---- fold Mtf = bf16(A + q*C) into LDS (f32 math; proven numerics) ----
    const float* qbase = q + (size_t)bb * E;
    for (int u = tid; u < 640; u += 512) {
        const int cc = u >> 6, ln = u & 63;
        const int i0 = (cc & 1) * 32 + (ln >> 4) * 8;
        const float4 a0 = *(const float4*)(Af + u * 8);
        const float4 a1 = *(const float4*)(Af + u * 8 + 4);
        const float4 c0 = *(const float4*)(Cf + u * 8);
        const float4 c1 = *(const float4*)(Cf + u * 8 + 4);
        const float4 q0 = *(const float4*)(qbase + i0);
        const float4 q1 = *(const float4*)(qbase + i0 + 4);
        short8 h;
        h[0] = (short)f2bu(a0.x + q0.x * c0.x);
        h[1] = (short)f2bu(a0.y + q0.y * c0.y);
        h[2] = (short)f2bu(a0.z + q0.z * c0.z);
        h[3] = (short)f2bu(a0.w + q0.w * c0.w);
        h[4] = (short)f2bu(a1.x + q1.x * c1.x);
        h[5] = (short)f2bu(a1.y + q1.y * c1.y);
        h[6] = (short)f2bu(a1.z + q1.z * c1.z);
        h[7] = (short)f2bu(a1.w + q1.w * c1.w);
        Mt[u] = h;
    }

    // ---- per-batch setup ----
    const int flagv = flagG[0];
    float cqr[5];
    #pragma unroll
    for (int nt = 0; nt < 5; ++nt)
        cqr[nt] = cq_all[(size_t)bb * H1N + nt * 16 + c];
    float b2r[3], wfr[3];
    #pragma unroll
    for (int nt2 = 0; nt2 < 3; ++nt2) {
        const int nc = nt2 * 16 + c;
        b2r[nt2] = (nc < H2N) ? b2[nc] : 0.f;
        wfr[nt2] = (nc < H2N) ? Wf[nc] : 0.f;
    }
    const float bf0 = bfp[0];
    const short8* W2v = (const short8*)W2fG;
    const float*  kbase = kmat + (size_t)bb * (L * E);
    const float*  vb    = vmat + (size_t)bb * (L * E);

    // ---- PREFETCH tile A (t=wv) k+v BEFORE the barrier ----
    const int rowA = 16 * wv;
    const float4* kpa = (const float4*)(kbase + (size_t)min(rowA + c, L - 1) * E);
    const float4 ka0 = kpa[2 * g];
    const float4 ka1 = kpa[2 * g + 1];
    const float4 ka2 = kpa[8 + 2 * g];
    const float4 ka3 = kpa[8 + 2 * g + 1];
    const float4 va0 = *(const float4*)(vb + (size_t)min(rowA + 0 + g, L - 1) * E + c * 4);
    const float4 va1 = *(const float4*)(vb + (size_t)min(rowA + 4 + g, L - 1) * E + c * 4);
    const float4 va2 = *(const float4*)(vb + (size_t)min(rowA + 8 + g, L - 1) * E + c * 4);
    const float4 va3 = *(const float4*)(vb + (size_t)min(rowA + 12 + g, L - 1) * E + c * 4);
    __builtin_amdgcn_sched_barrier(0);   // PIN: loads may not sink past this point
    __syncthreads();

    float s_w = 0.f;
    f32x4 oa = f32x4{0.f, 0.f, 0.f, 0.f};

    // ================= tile A (t = wv, always valid) =================
    float4 kb0, kb1, kb2, kb3, vb0, vb1, vb2, vb3;   // tile-B prefetch regs
    {
        const int row0 = rowA;

        // ---- issue tile-B k+v prefetch FIRST, then pin ----
        {
            const int tB = wv + 8;     // may be >=13; clamped rows keep loads in-bounds
            const int rowB = 16 * tB;
            const float4* kpb = (const float4*)(kbase + (size_t)min(rowB + c, L - 1) * E);
            kb0 = kpb[2 * g];
            kb1 = kpb[2 * g + 1];
            kb2 = kpb[8 + 2 * g];
            kb3 = kpb[8 + 2 * g + 1];
            vb0 = *(const float4*)(vb + (size_t)min(rowB + 0 + g, L - 1) * E + c * 4);
            vb1 = *(const float4*)(vb + (size_t)min(rowB + 4 + g, L - 1) * E + c * 4);
            vb2 = *(const float4*)(vb + (size_t)min(rowB + 8 + g, L - 1) * E + c * 4);
            vb3 = *(const float4*)(vb + (size_t)min(rowB + 12 + g, L - 1) * E + c * 4);
        }
        __builtin_amdgcn_sched_barrier(0);   // PIN tile-B loads here (issue-early)

        short8 ak0, ak1;
        ak0[0] = (short)f2bu(ka0.x); ak0[1] = (short)f2bu(ka0.y);
        ak0[2] = (short)f2bu(ka0.z); ak0[3] = (short)f2bu(ka0.w);
        ak0[4] = (short)f2bu(ka1.x); ak0[5] = (short)f2bu(ka1.y);
        ak0[6] = (short)f2bu(ka1.z); ak0[7] = (short)f2bu(ka1.w);
        ak1[0] = (short)f2bu(ka2.x); ak1[1] = (short)f2bu(ka2.y);
        ak1[2] = (short)f2bu(ka2.z); ak1[3] = (short)f2bu(ka2.w);
        ak1[4] = (short)f2bu(ka3.x); ak1[5] = (short)f2bu(ka3.y);
        ak1[6] = (short)f2bu(ka3.z); ak1[7] = (short)f2bu(ka3.w);

        f32x4 acc1[5];
        #pragma unroll
        for (int nt = 0; nt < 5; ++nt) acc1[nt] = f32x4{0.f, 0.f, 0.f, 0.f};
        #pragma unroll
        for (int nt = 0; nt < 5; ++nt) {
            acc1[nt] = __builtin_amdgcn_mfma_f32_16x16x32_bf16(ak0, Mt[(nt * 2 + 0) * 64 + lane], acc1[nt], 0, 0, 0);
            acc1[nt] = __builtin_amdgcn_mfma_f32_16x16x32_bf16(ak1, Mt[(nt * 2 + 1) * 64 + lane], acc1[nt], 0, 0, 0);
        }

        #pragma unroll
        for (int nt = 0; nt < 5; ++nt)
            #pragma unroll
            for (int r = 0; r < 4; ++r)
                H1t[wv][4 * g + r][nt * 16 + c] = f2bu(acc1[nt][r] + cqr[nt]);

        f32x4 acc2[3];
        #pragma unroll
        for (int nt2 = 0; nt2 < 3; ++nt2) acc2[nt2] = f32x4{0.f, 0.f, 0.f, 0.f};
        #pragma unroll
        for (int ks2 = 0; ks2 < 3; ++ks2) {
            const short8 a2 = *(const short8*)&H1t[wv][c][ks2 * 32 + g * 8];
            #pragma unroll
            for (int nt2 = 0; nt2 < 3; ++nt2)
                acc2[nt2] = __builtin_amdgcn_mfma_f32_16x16x32_bf16(a2, W2v[(nt2 * 3 + ks2) * 64 + lane], acc2[nt2], 0, 0, 0);
        }

        float pl0 = 0.f, pl1 = 0.f, pl2 = 0.f, pl3 = 0.f;
        #pragma unroll
        for (int nt2 = 0; nt2 < 3; ++nt2) {
            const float wfv = wfr[nt2], b2v = b2r[nt2];
            pl0 += wfv * __builtin_amdgcn_rcpf(1.f + __expf(-(acc2[nt2][0] + b2v)));
            pl1 += wfv * __builtin_amdgcn_rcpf(1.f + __expf(-(acc2[nt2][1] + b2v)));
            pl2 += wfv * __builtin_amdgcn_rcpf(1.f + __expf(-(acc2[nt2][2] + b2v)));
            pl3 += wfv * __builtin_amdgcn_rcpf(1.f + __expf(-(acc2[nt2][3] + b2v)));
        }
        ROR_ADD(pl0, 0x128); ROR_ADD(pl0, 0x124); ROR_ADD(pl0, 0x122); ROR_ADD(pl0, 0x121);
        ROR_ADD(pl1, 0x128); ROR_ADD(pl1, 0x124); ROR_ADD(pl1, 0x122); ROR_ADD(pl1, 0x121);
        ROR_ADD(pl2, 0x128); ROR_ADD(pl2, 0x124); ROR_ADD(pl2, 0x122); ROR_ADD(pl2, 0x121);
        ROR_ADD(pl3, 0x128); ROR_ADD(pl3, 0x124); ROR_ADD(pl3, 0x122); ROR_ADD(pl3, 0x121);

        // p = (mask || invalid row) ? 0 : exp(logit); bounded logit, no max needed.
        float p = 0.f;
        const int rowi = row0 + 4 * g + c;
        if (c < 4 && rowi < L) {
            const float myv = (c == 0) ? pl0 : (c == 1) ? pl1 : (c == 2) ? pl2 : pl3;
            const size_t mi = (size_t)bb * L + rowi;
            const int mv = flagv ? ((const int*)mask)[mi]
                                 : (int)((const unsigned char*)mask)[mi];
            if (!mv) p = __expf(bf0 + myv);
        }
        float ps = p;
        #pragma unroll
        for (int off = 1; off < 64; off <<= 1)
            ps += __shfl_xor(ps, off);
        s_w += ps;

        // p for row 4*rr+g lives in lane 16*rr+g  (register broadcast, no LDS)
        const float p0 = __shfl(p,  0 + g);
        const float p1 = __shfl(p, 16 + g);
        const float p2 = __shfl(p, 32 + g);
        const float p3 = __shfl(p, 48 + g);
        oa[0] += p0 * va0.x + p1 * va1.x + p2 * va2.x + p3 * va3.x;
        oa[1] += p0 * va0.y + p1 * va1.y + p2 * va2.y + p3 * va3.y;
        oa[2] += p0 * va0.z + p1 * va1.z + p2 * va2.z + p3 * va3.z;
        oa[3] += p0 * va0.w + p1 * va1.w + p2 * va2.w + p3 * va3.w;
    }

    // ================= tile B (t = wv + 8, valid for wv < 5) =================
    if (wv + 8 < 13) {
        const int row0 = 16 * (wv + 8);
        short8 ak0, ak1;
        ak0[0] = (short)f2bu(kb0.x); ak0[1] = (short)f2bu(kb0.y);
        ak0[2] = (short)f2bu(kb0.z); ak0[3] = (short)f2bu(kb0.w);
        ak0[4] = (short)f2bu(kb1.x); ak0[5] = (short)f2bu(kb1.y);
        ak0[6] = (short)f2bu(kb1.z); ak0[7] = (short)f2bu(kb1.w);
        ak1[0] = (short)f2bu(kb2.x); ak1[1] = (short)f2bu(kb2.y);
        ak1[2] = (short)f2bu(kb2.z); ak1[3] = (short)f2bu(kb2.w);
        ak1[4] = (short)f2bu(kb3.x); ak1[5] = (short)f2bu(kb3.y);
        ak1[6] = (short)f2bu(kb3.z); ak1[7] = (short)f2bu(kb3.w);

        f32x4 acc1[5];
        #pragma unroll
        for (int nt = 0; nt < 5; ++nt) acc1[nt] = f32x4{0.f, 0.f, 0.f, 0.f};
        #pragma unroll
        for (int nt = 0; nt < 5; ++nt) {
            acc1[nt] = __builtin_amdgcn_mfma_f32_16x16x32_bf16(ak0, Mt[(nt * 2 + 0) * 64 + lane], acc1[nt], 0, 0, 0);
            acc1[nt] = __builtin_amdgcn_mfma_f32_16x16x32_bf16(ak1, Mt[(nt * 2 + 1) * 64 + lane], acc1[nt], 0, 0, 0);
        }

        #pragma unroll
        for (int nt = 0; nt < 5; ++nt)
            #pragma unroll
            for (int r = 0; r < 4; ++r)
                H1t[wv][4 * g + r][nt * 16 + c] = f2bu(acc1[nt][r] + cqr[nt]);

        f32x4 acc2[3];
        #pragma unroll
        for (int nt2 = 0; nt2 < 3; ++nt2) acc2[nt2] = f32x4{0.f, 0.f, 0.f, 0.f};
        #pragma unroll
        for (int ks2 = 0; ks2 < 3; ++ks2) {
            const short8 a2 = *(const short8*)&H1t[wv][c][ks2 * 32 + g * 8];
            #pragma unroll
            for (int nt2 = 0; nt2 < 3; ++nt2)
                acc2[nt2] = __builtin_amdgcn_mfma_f32_16x16x32_bf16(a2, W2v[(nt2 * 3 + ks2) * 64 + lane], acc2[nt2], 0, 0, 0);
        }

        float pl0 = 0.f, pl1 = 0.f, pl2 = 0.f, pl3 = 0.f;
        #pragma unroll
        for (int nt2 = 0; nt2 < 3; ++nt2) {
            const float wfv = wfr[nt2], b2v = b2r[nt2];
            pl0 += wfv * __builtin_amdgcn_rcpf(1.f + __expf(-(acc2[nt2][0] + b2v)));
            pl1 += wfv * __builtin_amdgcn_rcpf(1.f + __expf(-(acc2[nt2][1] + b2v)));
            pl2 += wfv * __builtin_amdgcn_rcpf(1.f + __expf(-(acc2[nt2][2] + b2v)));
            pl3 += wfv * __builtin_amdgcn_rcpf(1.f + __expf(-(acc2[nt2][3] + b2v)));
        }
        ROR_ADD(pl0, 0x128); ROR_ADD(pl0, 0x124); ROR_ADD(pl0, 0x122); ROR_ADD(pl0, 0x121);
        ROR_ADD(pl1, 0x128); ROR_ADD(pl1, 0x124); ROR_ADD(pl1, 0x122); ROR_ADD(pl1, 0x121);
        ROR_ADD(pl2, 0x128); ROR_ADD(pl2, 0x124); ROR_ADD(pl2, 0x122); ROR_ADD(pl2, 0x121);
        ROR_ADD(pl3, 0x128); ROR_ADD(pl3, 0x124); ROR_ADD(pl3, 0x122); ROR_ADD(pl3, 0x121);

        float p = 0.f;
        const int rowi = row0 + 4 * g + c;
        if (c < 4 && rowi < L) {
            const float myv = (c == 0) ? pl0 : (c == 1) ? pl1 : (c == 2) ? pl2 : pl3;
            const size_t mi = (size_t)bb * L + rowi;
            const int mv = flagv ? ((const int*)mask)[mi]
                                 : (int)((const unsigned char*)mask)[mi];
            if (!mv) p = __expf(bf0 + myv);
        }
        float ps = p;
        #pragma unroll
        for (int off = 1; off < 64; off <<= 1)
            ps += __shfl_xor(ps, off);
        s_w += ps;

        const float p0 = __shfl(p,  0 + g);
        const float p1 = __shfl(p, 16 + g);
        const float p2 = __shfl(p, 32 + g);
        const float p3 = __shfl(p, 48 + g);
        oa[0] += p0 * vb0.x + p1 * vb1.x + p2 * vb2.x + p3 * vb3.x;
        oa[1] += p0 * vb0.y + p1 * vb1.y + p2 * vb2.y + p3 * vb3.y;
        oa[2] += p0 * vb0.z + p1 * vb1.z + p2 * vb2.z + p3 * vb3.z;
        oa[3] += p0 * vb0.w + p1 * vb1.w + p2 * vb2.w + p3 * vb3.w;
    }

    // ---- publish per-wave (s, oa) and combine once ----
    #pragma unroll
    for (int j = 0; j < 4; ++j) {
        oa[j] += __shfl_xor(oa[j], 16);
        oa[j] += __shfl_xor(oa[j], 32);
    }
    if (lane < 16)
        *(float4*)&comb_p[wv][4 * lane] = make_float4(oa[0], oa[1], oa[2], oa[3]);
    if (lane == 0) comb_s[wv] = s_w;
    __syncthreads();

    if (tid < 64) {
        float den = comb_s[0];
        float num = comb_p[0][tid];
        #pragma unroll
        for (int w = 1; w < 8; ++w) {
            den += comb_s[w];
            num += comb_p[w][tid];
        }
        out[(size_t)bb * E + tid] = num / den;
    }
}

} // namespace

extern "C" void kernel_launch(void* const* d_in, const int* in_sizes, int n_in,
                              void* d_out, int out_size, void* d_ws, size_t ws_size,
                              hipStream_t stream) {
    const float* q  = (const float*)d_in[0];
    const float* k  = (const float*)d_in[1];
    const float* v  = (const float*)d_in[2];
    const void*  mk = d_in[3];
    const float* W1 = (const float*)d_in[4];
    const float* b1 = (const float*)d_in[5];
    const float* W2 = (const float*)d_in[6];
    const float* b2 = (const float*)d_in[7];
    const float* Wf = (const float*)d_in[8];
    const float* bf = (const float*)d_in[9];
    float* out = (float*)d_out;

    const int B = in_sizes[0] / E;   // 4096

    char* ws = (char*)d_ws;
    float*          Af     = (float*)(ws + WS_AF);
    float*          Cf     = (float*)(ws + WS_CF);
    unsigned short* W2f    = (unsigned short*)(ws + WS_W2F);
    int*            flagG  = (int*)(ws + WS_FLAG);
    float*          cq_all = (float*)(ws + WS_CQ);

    const int prep_ids = 1216 + B * 20 + 1;
    k0_prep<<<(prep_ids + 255) / 256, 256, 0, stream>>>(W1, W2, q, b1, mk,
                                                        Af, Cf, W2f, cq_all, flagG, B);
    attn_main<<<B, 512, 0, stream>>>(q, k, v, mk, b2, Wf, bf,
                                     Af, Cf, W2f, cq_all, flagG, out);
}

// Round 17
// 121.356 us; speedup vs baseline: 1.0308x; 1.0002x over previous
//
#include <hip/hip_runtime.h>
#include <hip/hip_bf16.h>
#include <math.h>

namespace {

constexpr int L   = 200;
constexpr int E   = 64;
constexpr int H1N = 80;
constexpr int H2N = 40;

using short8 = __attribute__((ext_vector_type(8))) short;
using f32x4  = __attribute__((ext_vector_type(4))) float;

__device__ inline unsigned short f2bu(float f) {
    return (unsigned short)__builtin_bit_cast(short, __float2bfloat16(f));   // HW RNE
}

// DPP row_ror add: x += ror_n(x) within each 16-lane row (VALU pipe)
#define ROR_ADD(x, CTRL) do {                                                   \
    int _t = __builtin_amdgcn_update_dpp(0, __builtin_bit_cast(int, (x)),       \
                                         (CTRL), 0xf, 0xf, true);               \
    (x) += __builtin_bit_cast(float, _t); } while (0)

// ---- workspace layout (bytes) ----
constexpr int WS_AF   = 0;        // f32[640*8]  A=(W1_k-W1_d), GEMM1 frag order (K=64)
constexpr int WS_CF   = 20480;    // f32[640*8]  C=W1_p,        GEMM1 frag order
constexpr int WS_W2F  = 40960;    // bf16[576*8] GEMM2 B-frags
constexpr int WS_FLAG = 50176;    // int: 1 if mask is int32, 0 if bytes
constexpr int WS_CQ   = 50432;    // f32 [B][80] cq

// ---- prep: frag packing + cq GEMV + mask-dtype sniff (unchanged) ----
__global__ void k0_prep(const float* __restrict__ W1,
                        const float* __restrict__ W2,
                        const float* __restrict__ q,
                        const float* __restrict__ b1,
                        const void* __restrict__ mask,
                        float* __restrict__ Af,
                        float* __restrict__ Cf,
                        unsigned short* __restrict__ W2f,
                        float* __restrict__ cq_all,
                        int* __restrict__ flagG, int B)
{
    const int id = blockIdx.x * 256 + threadIdx.x;
    if (id < 640) {
        const int u  = id, cc = u >> 6, ln = u & 63;
        const int nt = cc >> 1, ks = cc & 1;
        const int j  = nt * 16 + (ln & 15);
        const int i0 = ks * 32 + (ln >> 4) * 8;
        #pragma unroll
        for (int e = 0; e < 8; ++e) {
            const int i = i0 + e;
            Af[u * 8 + e] = W1[(E + i) * H1N + j] - W1[(2 * E + i) * H1N + j];
            Cf[u * 8 + e] = W1[(3 * E + i) * H1N + j];
        }
    } else if (id < 1216) {
        const int u   = id - 640, cc = u >> 6, ln = u & 63;
        const int nt2 = cc / 3, ks2 = cc % 3;
        const int n   = nt2 * 16 + (ln & 15);
        const int j0  = ks2 * 32 + (ln >> 4) * 8;
        #pragma unroll
        for (int e = 0; e < 8; ++e) {
            const int j = j0 + e;
            W2f[u * 8 + e] = (j < H1N && n < H2N) ? f2bu(W2[j * H2N + n])
                                                  : (unsigned short)0;
        }
    } else {
        const int t = id - 1216;
        if (t > B * 20) return;
        if (t == B * 20) {   // mask dtype sniff, once per launch
            const unsigned char* mb = (const unsigned char*)mask;
            int isI32 = 1;
            for (int i = 0; i < 256; ++i)
                if ((i & 3) && mb[i]) { isI32 = 0; break; }
            flagG[0] = isI32;
            return;
        }
        const int b  = t / 20;
        const int jq = (t - b * 20) * 4;
        const float* qb = q + (size_t)b * E;
        float4 a = *(const float4*)(b1 + jq);
        #pragma unroll 8
        for (int i = 0; i < E; ++i) {
            const float qv = qb[i];
            const float4 wa = *(const float4*)(W1 + i * H1N + jq);
            const float4 wb = *(const float4*)(W1 + (2 * E + i) * H1N + jq);
            a.x += qv * (wa.x + wb.x);
            a.y += qv * (wa.y + wb.y);
            a.z += qv * (wa.z + wb.z);
            a.w += qv * (wa.w + wb.w);
        }
        *(float4*)(cq_all + (size_t)b * H1N + jq) = a;
    }
}

// R16 (passed, 121.4us), ONE change: tile-B k/v loads moved BEFORE __syncthreads.
// The barrier is a memory fence the compiler cannot sink loads across (proven:
// tile-A prefetch survived in R13-R16 while every post-barrier prefetch was sunk).
// All 16 float4 loads per lane are now in flight during the MLP compute.
__global__ __launch_bounds__(512, 2)
void attn_main(const float* __restrict__ q,
               const float* __restrict__ kmat,
               const float* __restrict__ vmat,
               const void* __restrict__ mask,
               const float* __restrict__ b2,
               const float* __restrict__ Wf,
               const float* __restrict__ bfp,
               const float* __restrict__ Af,
               const float* __restrict__ Cf,
               const unsigned short* __restrict__ W2fG,
               const float* __restrict__ cq_all,
               const int* __restrict__ flagG,
               float* __restrict__ out)
{
    const int tid  = threadIdx.x;
    const int lane = tid & 63;
    const int wv   = tid >> 6;        // 0..7
    const int g    = lane >> 4;
    const int c    = lane & 15;

    __shared__ short8 Mt[640];                   // 10240 B
    __shared__ unsigned short H1t[8][16][104];   // 26624 B
    __shared__ float comb_p[8][64];              //  2048 B
    __shared__ float comb_s[8];

    const int bb = blockIdx.x;                   // one batch per block

    *(unsigned long long*)&H1t[wv][c][80 + g * 4] = 0ULL;   // K-pad cols 80..95

    // ---- fold Mtf = bf16(A + q*C) into LDS (f32 math; proven numerics) ----
    const float* qbase = q + (size_t)bb * E;
    for (int u = tid; u < 640; u += 512) {
        const int cc = u >> 6, ln = u & 63;
        const int i0 = (cc & 1) * 32 + (ln >> 4) * 8;
        const float4 a0 = *(const float4*)(Af + u * 8);
        const float4 a1 = *(const float4*)(Af + u * 8 + 4);
        const float4 c0 = *(const float4*)(Cf + u * 8);
        const float4 c1 = *(const float4*)(Cf + u * 8 + 4);
        const float4 q0 = *(const float4*)(qbase + i0);
        const float4 q1 = *(const float4*)(qbase + i0 + 4);
        short8 h;
        h[0] = (short)f2bu(a0.x + q0.x * c0.x);
        h[1] = (short)f2bu(a0.y + q0.y * c0.y);
        h[2] = (short)f2bu(a0.z + q0.z * c0.z);
        h[3] = (short)f2bu(a0.w + q0.w * c0.w);
        h[4] = (short)f2bu(a1.x + q1.x * c1.x);
        h[5] = (short)f2bu(a1.y + q1.y * c1.y);
        h[6] = (short)f2bu(a1.z + q1.z * c1.z);
        h[7] = (short)f2bu(a1.w + q1.w * c1.w);
        Mt[u] = h;
    }

    // ---- per-batch setup ----
    const int flagv = flagG[0];
    float cqr[5];
    #pragma unroll
    for (int nt = 0; nt < 5; ++nt)
        cqr[nt] = cq_all[(size_t)bb * H1N + nt * 16 + c];
    float b2r[3], wfr[3];
    #pragma unroll
    for (int nt2 = 0; nt2 < 3; ++nt2) {
        const int nc = nt2 * 16 + c;
        b2r[nt2] = (nc < H2N) ? b2[nc] : 0.f;
        wfr[nt2] = (nc < H2N) ? Wf[nc] : 0.f;
    }
    const float bf0 = bfp[0];
    const short8* W2v = (const short8*)W2fG;
    const float*  kbase = kmat + (size_t)bb * (L * E);
    const float*  vb    = vmat + (size_t)bb * (L * E);

    // ---- PREFETCH BOTH tiles' k+v BEFORE the barrier (barrier pins all 16 loads) ----
    const int rowA = 16 * wv;
    const int rowB = 16 * (wv + 8);              // may exceed L; all uses clamped
    const float4* kpa = (const float4*)(kbase + (size_t)min(rowA + c, L - 1) * E);
    const float4 ka0 = kpa[2 * g];
    const float4 ka1 = kpa[2 * g + 1];
    const float4 ka2 = kpa[8 + 2 * g];
    const float4 ka3 = kpa[8 + 2 * g + 1];
    const float4* kpb = (const float4*)(kbase + (size_t)min(rowB + c, L - 1) * E);
    const float4 kb0 = kpb[2 * g];
    const float4 kb1 = kpb[2 * g + 1];
    const float4 kb2 = kpb[8 + 2 * g];
    const float4 kb3 = kpb[8 + 2 * g + 1];
    const float4 va0 = *(const float4*)(vb + (size_t)min(rowA + 0 + g, L - 1) * E + c * 4);
    const float4 va1 = *(const float4*)(vb + (size_t)min(rowA + 4 + g, L - 1) * E + c * 4);
    const float4 va2 = *(const float4*)(vb + (size_t)min(rowA + 8 + g, L - 1) * E + c * 4);
    const float4 va3 = *(const float4*)(vb + (size_t)min(rowA + 12 + g, L - 1) * E + c * 4);
    const float4 vb0 = *(const float4*)(vb + (size_t)min(rowB + 0 + g, L - 1) * E + c * 4);
    const float4 vb1 = *(const float4*)(vb + (size_t)min(rowB + 4 + g, L - 1) * E + c * 4);
    const float4 vb2 = *(const float4*)(vb + (size_t)min(rowB + 8 + g, L - 1) * E + c * 4);
    const float4 vb3 = *(const float4*)(vb + (size_t)min(rowB + 12 + g, L - 1) * E + c * 4);
    __builtin_amdgcn_sched_barrier(0);   // keep load cluster at top of region
    __syncthreads();                      // memory fence: loads cannot sink past

    float s_w = 0.f;
    f32x4 oa = f32x4{0.f, 0.f, 0.f, 0.f};

    // ================= tile A (t = wv, always valid) =================
    {
        const int row0 = rowA;
        short8 ak0, ak1;
        ak0[0] = (short)f2bu(ka0.x); ak0[1] = (short)f2bu(ka0.y);
        ak0[2] = (short)f2bu(ka0.z); ak0[3] = (short)f2bu(ka0.w);
        ak0[4] = (short)f2bu(ka1.x); ak0[5] = (short)f2bu(ka1.y);
        ak0[6] = (short)f2bu(ka1.z); ak0[7] = (short)f2bu(ka1.w);
        ak1[0] = (short)f2bu(ka2.x); ak1[1] = (short)f2bu(ka2.y);
        ak1[2] = (short)f2bu(ka2.z); ak1[3] = (short)f2bu(ka2.w);
        ak1[4] = (short)f2bu(ka3.x); ak1[5] = (short)f2bu(ka3.y);
        ak1[6] = (short)f2bu(ka3.z); ak1[7] = (short)f2bu(ka3.w);

        f32x4 acc1[5];
        #pragma unroll
        for (int nt = 0; nt < 5; ++nt) acc1[nt] = f32x4{0.f, 0.f, 0.f, 0.f};
        #pragma unroll
        for (int nt = 0; nt < 5; ++nt) {
            acc1[nt] = __builtin_amdgcn_mfma_f32_16x16x32_bf16(ak0, Mt[(nt * 2 + 0) * 64 + lane], acc1[nt], 0, 0, 0);
            acc1[nt] = __builtin_amdgcn_mfma_f32_16x16x32_bf16(ak1, Mt[(nt * 2 + 1) * 64 + lane], acc1[nt], 0, 0, 0);
        }

        #pragma unroll
        for (int nt = 0; nt < 5; ++nt)
            #pragma unroll
            for (int r = 0; r < 4; ++r)
                H1t[wv][4 * g + r][nt * 16 + c] = f2bu(acc1[nt][r] + cqr[nt]);

        f32x4 acc2[3];
        #pragma unroll
        for (int nt2 = 0; nt2 < 3; ++nt2) acc2[nt2] = f32x4{0.f, 0.f, 0.f, 0.f};
        #pragma unroll
        for (int ks2 = 0; ks2 < 3; ++ks2) {
            const short8 a2 = *(const short8*)&H1t[wv][c][ks2 * 32 + g * 8];
            #pragma unroll
            for (int nt2 = 0; nt2 < 3; ++nt2)
                acc2[nt2] = __builtin_amdgcn_mfma_f32_16x16x32_bf16(a2, W2v[(nt2 * 3 + ks2) * 64 + lane], acc2[nt2], 0, 0, 0);
        }

        float pl0 = 0.f, pl1 = 0.f, pl2 = 0.f, pl3 = 0.f;
        #pragma unroll
        for (int nt2 = 0; nt2 < 3; ++nt2) {
            const float wfv = wfr[nt2], b2v = b2r[nt2];
            pl0 += wfv * __builtin_amdgcn_rcpf(1.f + __expf(-(acc2[nt2][0] + b2v)));
            pl1 += wfv * __builtin_amdgcn_rcpf(1.f + __expf(-(acc2[nt2][1] + b2v)));
            pl2 += wfv * __builtin_amdgcn_rcpf(1.f + __expf(-(acc2[nt2][2] + b2v)));
            pl3 += wfv * __builtin_amdgcn_rcpf(1.f + __expf(-(acc2[nt2][3] + b2v)));
        }
        ROR_ADD(pl0, 0x128); ROR_ADD(pl0, 0x124); ROR_ADD(pl0, 0x122); ROR_ADD(pl0, 0x121);
        ROR_ADD(pl1, 0x128); ROR_ADD(pl1, 0x124); ROR_ADD(pl1, 0x122); ROR_ADD(pl1, 0x121);
        ROR_ADD(pl2, 0x128); ROR_ADD(pl2, 0x124); ROR_ADD(pl2, 0x122); ROR_ADD(pl2, 0x121);
        ROR_ADD(pl3, 0x128); ROR_ADD(pl3, 0x124); ROR_ADD(pl3, 0x122); ROR_ADD(pl3, 0x121);

        float p = 0.f;
        const int rowi = row0 + 4 * g + c;
        if (c < 4 && rowi < L) {
            const float myv = (c == 0) ? pl0 : (c == 1) ? pl1 : (c == 2) ? pl2 : pl3;
            const size_t mi = (size_t)bb * L + rowi;
            const int mv = flagv ? ((const int*)mask)[mi]
                                 : (int)((const unsigned char*)mask)[mi];
            if (!mv) p = __expf(bf0 + myv);
        }
        float ps = p;
        #pragma unroll
        for (int off = 1; off < 64; off <<= 1)
            ps += __shfl_xor(ps, off);
        s_w += ps;

        const float p0 = __shfl(p,  0 + g);
        const float p1 = __shfl(p, 16 + g);
        const float p2 = __shfl(p, 32 + g);
        const float p3 = __shfl(p, 48 + g);
        oa[0] += p0 * va0.x + p1 * va1.x + p2 * va2.x + p3 * va3.x;
        oa[1] += p0 * va0.y + p1 * va1.y + p2 * va2.y + p3 * va3.y;
        oa[2] += p0 * va0.z + p1 * va1.z + p2 * va2.z + p3 * va3.z;
        oa[3] += p0 * va0.w + p1 * va1.w + p2 * va2.w + p3 * va3.w;
    }

    // ================= tile B (t = wv + 8, valid for wv < 5) =================
    if (wv + 8 < 13) {
        const int row0 = rowB;
        short8 ak0, ak1;
        ak0[0] = (short)f2bu(kb0.x); ak0[1] = (short)f2bu(kb0.y);
        ak0[2] = (short)f2bu(kb0.z); ak0[3] = (short)f2bu(kb0.w);
        ak0[4] = (short)f2bu(kb1.x); ak0[5] = (short)f2bu(kb1.y);
        ak0[6] = (short)f2bu(kb1.z); ak0[7] = (short)f2bu(kb1.w);
        ak1[0] = (short)f2bu(kb2.x); ak1[1] = (short)f2bu(kb2.y);
        ak1[2] = (short)f2bu(kb2.z); ak1[3] = (short)f2bu(kb2.w);
        ak1[4] = (short)f2bu(kb3.x); ak1[5] = (short)f2bu(kb3.y);
        ak1[6] = (short)f2bu(kb3.z); ak1[7] = (short)f2bu(kb3.w);

        f32x4 acc1[5];
        #pragma unroll
        for (int nt = 0; nt < 5; ++nt) acc1[nt] = f32x4{0.f, 0.f, 0.f, 0.f};
        #pragma unroll
        for (int nt = 0; nt < 5; ++nt) {
            acc1[nt] = __builtin_amdgcn_mfma_f32_16x16x32_bf16(ak0, Mt[(nt * 2 + 0) * 64 + lane], acc1[nt], 0, 0, 0);
            acc1[nt] = __builtin_amdgcn_mfma_f32_16x16x32_bf16(ak1, Mt[(nt * 2 + 1) * 64 + lane], acc1[nt], 0, 0, 0);
        }

        #pragma unroll
        for (int nt = 0; nt < 5; ++nt)
            #pragma unroll
            for (int r = 0; r < 4; ++r)
                H1t[wv][4 * g + r][nt * 16 + c] = f2bu(acc1[nt][r] + cqr[nt]);

        f32x4 acc2[3];
        #pragma unroll
        for (int nt2 = 0; nt2 < 3; ++nt2) acc2[nt2] = f32x4{0.f, 0.f, 0.f, 0.f};
        #pragma unroll
        for (int ks2 = 0; ks2 < 3; ++ks2) {
            const short8 a2 = *(const short8*)&H1t[wv][c][ks2 * 32 + g * 8];
            #pragma unroll
            for (int nt2 = 0; nt2 < 3; ++nt2)
                acc2[nt2] = __builtin_amdgcn_mfma_f32_16x16x32_bf16(a2, W2v[(nt2 * 3 + ks2) * 64 + lane], acc2[nt2], 0, 0, 0);
        }

        float pl0 = 0.f, pl1 = 0.f, pl2 = 0.f, pl3 = 0.f;
        #pragma unroll
        for (int nt2 = 0; nt2 < 3; ++nt2) {
            const float wfv = wfr[nt2], b2v = b2r[nt2];
            pl0 += wfv * __builtin_amdgcn_rcpf(1.f + __expf(-(acc2[nt2][0] + b2v)));
            pl1 += wfv * __builtin_amdgcn_rcpf(1.f + __expf(-(acc2[nt2][1] + b2v)));
            pl2 += wfv * __builtin_amdgcn_rcpf(1.f + __expf(-(acc2[nt2][2] + b2v)));
            pl3 += wfv * __builtin_amdgcn_rcpf(1.f + __expf(-(acc2[nt2][3] + b2v)));
        }
        ROR_ADD(pl0, 0x128); ROR_ADD(pl0, 0x124); ROR_ADD(pl0, 0x122); ROR_ADD(pl0, 0x121);
        ROR_ADD(pl1, 0x128); ROR_ADD(pl1, 0x124); ROR_ADD(pl1, 0x122); ROR_ADD(pl1, 0x121);
        ROR_ADD(pl2, 0x128); ROR_ADD(pl2, 0x124); ROR_ADD(pl2, 0x122); ROR_ADD(pl2, 0x121);
        ROR_ADD(pl3, 0x128); ROR_ADD(pl3, 0x124); ROR_ADD(pl3, 0x122); ROR_ADD(pl3, 0x121);

        float p = 0.f;
        const int rowi = row0 + 4 * g + c;
        if (c < 4 && rowi < L) {
            const float myv = (c == 0) ? pl0 : (c == 1) ? pl1 : (c == 2) ? pl2 : pl3;
            const size_t mi = (size_t)bb * L + rowi;
            const int mv = flagv ? ((const int*)mask)[mi]
                                 : (int)((const unsigned char*)mask)[mi];
            if (!mv) p = __expf(bf0 + myv);
        }
        float ps = p;
        #pragma unroll
        for (int off = 1; off < 64; off <<= 1)
            ps += __shfl_xor(ps, off);
        s_w += ps;

        const float p0 = __shfl(p,  0 + g);
        const float p1 = __shfl(p, 16 + g);
        const float p2 = __shfl(p, 32 + g);
        const float p3 = __shfl(p, 48 + g);
        oa[0] += p0 * vb0.x + p1 * vb1.x + p2 * vb2.x + p3 * vb3.x;
        oa[1] += p0 * vb0.y + p1 * vb1.y + p2 * vb2.y + p3 * vb3.y;
        oa[2] += p0 * vb0.z + p1 * vb1.z + p2 * vb2.z + p3 * vb3.z;
        oa[3] += p0 * vb0.w + p1 * vb1.w + p2 * vb2.w + p3 * vb3.w;
    }

    // ---- publish per-wave (s, oa) and combine once ----
    #pragma unroll
    for (int j = 0; j < 4; ++j) {
        oa[j] += __shfl_xor(oa[j], 16);
        oa[j] += __shfl_xor(oa[j], 32);
    }
    if (lane < 16)
        *(float4*)&comb_p[wv][4 * lane] = make_float4(oa[0], oa[1], oa[2], oa[3]);
    if (lane == 0) comb_s[wv] = s_w;
    __syncthreads();

    if (tid < 64) {
        float den = comb_s[0];
        float num = comb_p[0][tid];
        #pragma unroll
        for (int w = 1; w < 8; ++w) {
            den += comb_s[w];
            num += comb_p[w][tid];
        }
        out[(size_t)bb * E + tid] = num / den;
    }
}

} // namespace

extern "C" void kernel_launch(void* const* d_in, const int* in_sizes, int n_in,
                              void* d_out, int out_size, void* d_ws, size_t ws_size,
                              hipStream_t stream) {
    const float* q  = (const float*)d_in[0];
    const float* k  = (const float*)d_in[1];
    const float* v  = (const float*)d_in[2];
    const void*  mk = d_in[3];
    const float* W1 = (const float*)d_in[4];
    const float* b1 = (const float*)d_in[5];
    const float* W2 = (const float*)d_in[6];
    const float* b2 = (const float*)d_in[7];
    const float* Wf = (const float*)d_in[8];
    const float* bf = (const float*)d_in[9];
    float* out = (float*)d_out;

    const int B = in_sizes[0] / E;   // 4096

    char* ws = (char*)d_ws;
    float*          Af     = (float*)(ws + WS_AF);
    float*          Cf     = (float*)(ws + WS_CF);
    unsigned short* W2f    = (unsigned short*)(ws + WS_W2F);
    int*            flagG  = (int*)(ws + WS_FLAG);
    float*          cq_all = (float*)(ws + WS_CQ);

    const int prep_ids = 1216 + B * 20 + 1;
    k0_prep<<<(prep_ids + 255) / 256, 256, 0, stream>>>(W1, W2, q, b1, mk,
                                                        Af, Cf, W2f, cq_all, flagG, B);
    attn_main<<<B, 512, 0, stream>>>(q, k, v, mk, b2, Wf, bf,
                                     Af, Cf, W2f, cq_all, flagG, out);
}